// Round 10
// baseline (50575.165 us; speedup 1.0000x reference)
//
#include <hip/hip_runtime.h>

// ---------------- constants ----------------
static constexpr int BB = 32, TI = 2000, TT = 1000, CIN = 80, F = 256, KW = 11;
static constexpr int G4 = 2048, V = 29;
static constexpr int MROWS = TT * BB;   // 32000
static constexpr int KC = 896;          // conv K (11*80=880) padded to mult of 64
static constexpr int CH = 100;          // steps per recurrence chunk
static constexpr int NCH = TT / CH;     // 10 chunks
static constexpr int CROWS = CH * BB;   // 3200 rows per chunk
static constexpr unsigned SENT = 0x7FC0u;            // bf16 NaN: h can never produce it
static constexpr unsigned SENT2 = 0x7FC07FC0u;

using short8 = __attribute__((ext_vector_type(8))) short;
using f32x4  = __attribute__((ext_vector_type(4))) float;
using u32x4  = __attribute__((ext_vector_type(4))) unsigned int;  // asm-friendly 128-bit

#define DEV __device__ __forceinline__

DEV ushort f2bf(float f) {
  unsigned u = __float_as_uint(f);
  unsigned r = (u + 0x7FFFu + ((u >> 16) & 1u)) >> 16;
  return (ushort)r;
}
DEV float bf2f(ushort h) { return __uint_as_float(((unsigned)h) << 16); }
DEV float sigm(float x) { return 1.f / (1.f + __expf(-x)); }
DEV float tanhft(float x) { return 1.f - 2.f / (__expf(2.f * x) + 1.f); }

// device-scope (MALL-coherent, sc1) wide ops for cross-block h exchange
DEV void ld64_sc1(const u32x4* p, u32x4* v) {
  asm volatile(
      "global_load_dwordx4 %0, %[a], off sc1\n\t"
      "global_load_dwordx4 %1, %[a], off offset:16 sc1\n\t"
      "global_load_dwordx4 %2, %[a], off offset:32 sc1\n\t"
      "global_load_dwordx4 %3, %[a], off offset:48 sc1\n\t"
      "s_waitcnt vmcnt(0)"
      : "=&v"(v[0]), "=&v"(v[1]), "=&v"(v[2]), "=&v"(v[3])
      : [a] "v"(p)
      : "memory");
}
DEV void st16_sc1(u32x4* p, u32x4 v) {
  asm volatile("global_store_dwordx4 %0, %1, off sc1" :: "v"(p), "v"(v) : "memory");
}

// any 16-bit half equals sentinel?
DEV int anysent(unsigned x) {
  unsigned y = x ^ SENT2;
  return ((y & 0xFFFFu) == 0u) | ((y >> 16) == 0u);
}
DEV int ok16(u32x4 v) {
  return !(anysent(v[0]) | anysent(v[1]) | anysent(v[2]) | anysent(v[3]));
}

// ---------------- prep kernels ----------------
// fill n8 * 8 ushorts with sentinel (uint4 = 8 bf16 per thread)
__global__ void k_fillsent(uint4* p, int n8) {
  int i = blockIdx.x * blockDim.x + threadIdx.x;
  if (i < n8) { uint4 s = {SENT2, SENT2, SENT2, SENT2}; p[i] = s; }
}

// conv_w [11][80][256] -> CW [256][896] bf16 (K padded w/ zeros)
__global__ void k_convw(const float* __restrict__ w, ushort* __restrict__ dst) {
  int idx = blockIdx.x * blockDim.x + threadIdx.x;
  if (idx >= F * KC) return;
  int f = idx / KC, kk = idx % KC;
  float v = (kk < KW * CIN) ? w[(size_t)kk * F + f] : 0.f;
  dst[idx] = f2bf(v);
}

// src [K][N] fp32 -> dst [N][K] bf16
__global__ void k_transp(const float* __restrict__ src, ushort* __restrict__ dst, int K, int N) {
  int idx = blockIdx.x * blockDim.x + threadIdx.x;
  if (idx >= K * N) return;
  int n = idx / K, k = idx % K;
  dst[idx] = f2bf(src[(size_t)k * N + n]);
}

// wh [512][2048] fp32 (f and b) -> packed MFMA B-fragments for the FAT-BLOCK rec kernel.
// idx = (((((d*4+fpart)*8+w)*4+cg)*16+kk)*64+lane)*8 + j
__global__ void k_whr(const float* __restrict__ whf, const float* __restrict__ whb,
                      ushort* __restrict__ dst) {
  int idx = blockIdx.x * blockDim.x + threadIdx.x;
  if (idx >= (1 << 21)) return;
  int j = idx & 7, lane = (idx >> 3) & 63, kk = (idx >> 9) & 15;
  int cg = (idx >> 13) & 3, w = (idx >> 15) & 7, fpart = (idx >> 18) & 3, d = (idx >> 20) & 1;
  int c16 = lane & 15, q = lane >> 4;
  int hc = fpart * 128 + w * 16 + cg * 4 + (c16 >> 2);
  int g = c16 & 3;
  int k = kk * 32 + q * 8 + j;
  int col = g * 512 + hc;
  const float* s = d ? whb : whf;
  dst[idx] = f2bf(s[(size_t)k * G4 + col]);
}

// x [32][2000][80] fp32 -> A0 [3200][896] bf16 im2col chunk (rows: (pos-pos0)*32+b)
__global__ void k_im2col(const float* __restrict__ x, ushort* __restrict__ A0, int pos0) {
  int idx = blockIdx.x * blockDim.x + threadIdx.x;
  if (idx >= CROWS * KC) return;
  int row = idx / KC, kk = idx % KC;
  int pos = pos0 + (row >> 5), b = row & 31;
  float v = 0.f;
  if (kk < KW * CIN) {
    int k = kk / CIN, c = kk % CIN;
    int tx = 2 * pos + k - 4;
    if (tx >= 0 && tx < TI) v = x[((size_t)b * TI + tx) * CIN + c];
  }
  A0[idx] = f2bf(v);
}

// ---------------- GEMM: C = A[.,K] * BT[N,K]^T + bias (bf16 in/out, fp32 acc) ----------
// grid (Mtiles, N/128). 128x128 tile, BK=64, 4 waves, 4x4 16x16 frags/wave.
// tmode=0: C[row*N+col] (optional relu). tmode=1: C[col*CROWS+row] packed 4-row stores.
__global__ __launch_bounds__(256, 2) void k_gemm(const ushort* __restrict__ A,
                                                 const ushort* __restrict__ BT,
                                                 const float* __restrict__ bias,
                                                 ushort* __restrict__ C,
                                                 int N, int K, int relu, int tmode) {
  __shared__ ushort As[128 * 64];
  __shared__ ushort Bs[128 * 64];
  const int tid = threadIdx.x;
  const int lane = tid & 63, wid = tid >> 6;
  const int wm = wid >> 1, wn = wid & 1;
  const int l16 = lane & 15, q = lane >> 4;
  const int bm = blockIdx.x, bn = blockIdx.y;
  const int srow = tid >> 1, scol = (tid & 1) * 32;
  const ushort* ga = A + (size_t)(bm * 128 + srow) * K + scol;
  const ushort* gb = BT + (size_t)(bn * 128 + srow) * K + scol;

  f32x4 acc[4][4] = {};
  uint4 va[4], vb[4];
#pragma unroll
  for (int i = 0; i < 4; i++) { va[i] = ((const uint4*)ga)[i]; vb[i] = ((const uint4*)gb)[i]; }

  for (int k0 = 0; k0 < K; k0 += 64) {
    __syncthreads();
#pragma unroll
    for (int i = 0; i < 4; i++) {
      *(uint4*)&As[srow * 64 + scol + i * 8] = va[i];
      *(uint4*)&Bs[srow * 64 + scol + i * 8] = vb[i];
    }
    __syncthreads();
    if (k0 + 64 < K) {
      const ushort* na = ga + k0 + 64;
      const ushort* nb = gb + k0 + 64;
#pragma unroll
      for (int i = 0; i < 4; i++) { va[i] = ((const uint4*)na)[i]; vb[i] = ((const uint4*)nb)[i]; }
    }
#pragma unroll
    for (int kk = 0; kk < 2; kk++) {
      short8 af[4], bf[4];
#pragma unroll
      for (int mt = 0; mt < 4; mt++)
        af[mt] = *(const short8*)&As[(wm * 64 + mt * 16 + l16) * 64 + kk * 32 + q * 8];
#pragma unroll
      for (int nt = 0; nt < 4; nt++)
        bf[nt] = *(const short8*)&Bs[(wn * 64 + nt * 16 + l16) * 64 + kk * 32 + q * 8];
#pragma unroll
      for (int mt = 0; mt < 4; mt++)
#pragma unroll
        for (int nt = 0; nt < 4; nt++)
          acc[mt][nt] = __builtin_amdgcn_mfma_f32_16x16x32_bf16(af[mt], bf[nt], acc[mt][nt], 0, 0, 0);
    }
  }
  if (tmode == 0) {
#pragma unroll
    for (int mt = 0; mt < 4; mt++) {
#pragma unroll
      for (int nt = 0; nt < 4; nt++) {
        int col = bn * 128 + wn * 64 + nt * 16 + l16;
        float bv = bias[col];
#pragma unroll
        for (int r = 0; r < 4; r++) {
          int row = bm * 128 + wm * 64 + mt * 16 + q * 4 + r;
          float v = acc[mt][nt][r] + bv;
          if (relu) v = fmaxf(v, 0.f);
          C[(size_t)row * N + col] = f2bf(v);
        }
      }
    }
  } else {
#pragma unroll
    for (int mt = 0; mt < 4; mt++) {
#pragma unroll
      for (int nt = 0; nt < 4; nt++) {
        int col = bn * 128 + wn * 64 + nt * 16 + l16;
        float bv = bias[col];
        ushort4 pk;
        pk.x = f2bf(acc[mt][nt][0] + bv);
        pk.y = f2bf(acc[mt][nt][1] + bv);
        pk.z = f2bf(acc[mt][nt][2] + bv);
        pk.w = f2bf(acc[mt][nt][3] + bv);
        int row = bm * 128 + wm * 64 + mt * 16 + q * 4;
        *(ushort4*)&C[(size_t)col * CROWS + row] = pk;
      }
    }
  }
}

// ---------------- persistent BiLSTM recurrence chunk (FAT BLOCKS) ----------
// 8 blocks x 512 threads; block = d*4 + fpart: fpart owns h-cols [fpart*128, fpart*128+128).
// wh slice = 256 VGPRs of pre-packed B-fragments (wf[4][16]). Per step per wave: 128 MFMAs.
// Sync: self-validating data (bf16-NaN sentinel pre-fill), batched sc1 poll-the-data.
__global__ __launch_bounds__(512, 1) void k_rec(const ushort* __restrict__ xgf,
                                                const ushort* __restrict__ xgb,
                                                const ushort* __restrict__ whr,
                                                ushort* __restrict__ hout,
                                                float* __restrict__ cstbuf,
                                                int s0) {
  __shared__ ushort hs[32 * 512];      // 32KB gather target, rows XOR-swizzled
  __shared__ ushort hstage[32 * 128];  // 8KB producer staging [row][local hcol]
  const int tid = threadIdx.x, lane = tid & 63, w = tid >> 6;
  const int fpart = blockIdx.x & 3, d = blockIdx.x >> 2;
  const int l16 = lane & 15, q = lane >> 4;
  const ushort* xg = d ? xgb : xgf;   // transposed layout [2048][CROWS]
  float* cs = cstbuf + ((size_t)blockIdx.x * 512 + tid) * 32;

  short8 wf[4][16];   // 256 VGPRs: B-fragments for this block's 128 cols x 4 gates
  {
    const ushort* p = whr + ((size_t)((d * 4 + fpart) * 8 + w) * 4) * 16 * 512 + (size_t)lane * 8;
#pragma unroll
    for (int cg = 0; cg < 4; cg++)
#pragma unroll
      for (int kk = 0; kk < 16; kk++)
        wf[cg][kk] = *(const short8*)(p + ((size_t)cg * 16 + kk) * 512);
  }
  const int g = l16 & 3;
  const int hcb = fpart * 128 + w * 16 + (l16 >> 2);  // + cg*4 per col-group
  float cst[4][2][4];
#pragma unroll
  for (int cg = 0; cg < 4; cg++)
#pragma unroll
    for (int mt = 0; mt < 2; mt++)
#pragma unroll
      for (int r = 0; r < 4; r++)
        cst[cg][mt][r] = (s0 == 0) ? 0.f : cs[cg * 8 + mt * 4 + r];

  for (int ls = 0; ls < CH; ls++) {
    const int s = s0 + ls;
    const int pos = d ? (999 - s) : s;
    const int lp = d ? (CH - 1 - ls) : ls;    // local row block in xg chunk buffer
    // prefetch xt from transposed xg (independent of h -> overlaps poll latency)
    ushort4 xt[4][2];
#pragma unroll
    for (int cg = 0; cg < 4; cg++) {
      const ushort* xc = xg + (size_t)(g * 512 + hcb + cg * 4) * CROWS + lp * 32 + q * 4;
      xt[cg][0] = *(const ushort4*)(xc);        // rows q*4+0..3    (mt=0)
      xt[cg][1] = *(const ushort4*)(xc + 16);   // rows 16+q*4+0..3 (mt=1)
    }

    if (s == 0) {
      uint4 z4 = {0, 0, 0, 0};
#pragma unroll
      for (int i = 0; i < 4; i++) ((uint4*)hs)[tid * 4 + i] = z4;
    } else {
      // gather h_prev: thread -> one 64B chunk (producer p4, row, col-chunk cc)
      const int p4 = tid >> 7, rem = tid & 127, row = rem >> 2, cc = rem & 3;
      const int ppos = d ? pos + 1 : pos - 1;
      const u32x4* gb = (const u32x4*)(hout + ((size_t)ppos * 32 + row) * 1024 +
                                       d * 512 + p4 * 128 + cc * 32);
      u32x4 v[4];
      int done = 0;
      do {
        if (!done) {
          ld64_sc1(gb, v);
          done = ok16(v[0]) & ok16(v[1]) & ok16(v[2]) & ok16(v[3]);
        }
      } while (!__all(done));
      const int swz = (row & 7) << 4;
      char* L = (char*)hs + row * 1024;
      const int cb = p4 * 256 + cc * 64;
#pragma unroll
      for (int k = 0; k < 4; k++)
        *(u32x4*)(L + ((cb + k * 16) ^ swz)) = v[k];
    }
    __syncthreads();

    f32x4 za[2][4] = {};
#pragma unroll
    for (int kk = 0; kk < 16; kk++) {
      short8 a[2];
#pragma unroll
      for (int mt = 0; mt < 2; mt++) {
        int row = mt * 16 + l16;
        int cb = kk * 64 + q * 16;
        a[mt] = *(const short8*)((char*)hs + row * 1024 + (cb ^ ((row & 7) << 4)));
      }
#pragma unroll
      for (int mt = 0; mt < 2; mt++)
#pragma unroll
        for (int cg = 0; cg < 4; cg++)
          za[mt][cg] = __builtin_amdgcn_mfma_f32_16x16x32_bf16(a[mt], wf[cg][kk], za[mt][cg], 0, 0, 0);
    }

#pragma unroll
    for (int cg = 0; cg < 4; cg++)
#pragma unroll
      for (int mt = 0; mt < 2; mt++)
#pragma unroll
        for (int r = 0; r < 4; r++) {
          int bt = mt * 16 + q * 4 + r;
          ushort xr = (r == 0) ? xt[cg][mt].x : (r == 1) ? xt[cg][mt].y
                     : (r == 2) ? xt[cg][mt].z : xt[cg][mt].w;
          float z = za[mt][cg][r] + bf2f(xr);
          int base = lane & ~3;
          float zi = __shfl(z, base + 0);
          float zf = __shfl(z, base + 1);
          float zg = __shfl(z, base + 2);
          float zo = __shfl(z, base + 3);
          float cn = sigm(zf) * cst[cg][mt][r] + sigm(zi) * tanhft(zg);
          cst[cg][mt][r] = cn;
          float hv = sigm(zo) * tanhft(cn);
          if (g == 0) hstage[bt * 128 + w * 16 + cg * 4 + (l16 >> 2)] = f2bf(hv);
        }
    __syncthreads();  // hstage complete (also orders prior LDS reads before overwrite)
    // coalesced producer store: 512 threads x 16B = full 8KB slice, sc1 fire-and-forget
    {
      const int row = tid >> 4, ck = tid & 15;
      u32x4 dv = *(u32x4*)((char*)hstage + row * 256 + ck * 16);
      st16_sc1((u32x4*)(hout + ((size_t)pos * 32 + row) * 1024 + d * 512 + fpart * 128) + ck, dv);
    }
  }
#pragma unroll
  for (int cg = 0; cg < 4; cg++)
#pragma unroll
    for (int mt = 0; mt < 2; mt++)
#pragma unroll
      for (int r = 0; r < 4; r++) cs[cg * 8 + mt * 4 + r] = cst[cg][mt][r];
}

// ---------------- dense: out[b][pos][29] = h2[row,1024] . W[1024,29] + bias ------------
__global__ __launch_bounds__(256, 2) void k_dense(const ushort* __restrict__ h2,
                                                  const float* __restrict__ wd,
                                                  const float* __restrict__ bd,
                                                  float* __restrict__ out) {
  __shared__ ushort rs[8 * 1024];
  const int tid = threadIdx.x;
  const int r0 = blockIdx.x * 8;
  const uint4* src = (const uint4*)(h2 + (size_t)r0 * 1024);
#pragma unroll
  for (int i = 0; i < 4; i++) ((uint4*)rs)[tid * 4 + i] = src[tid * 4 + i];
  __syncthreads();
  if (tid < 8 * V) {
    const int rr = tid / V, v = tid % V;
    float acc = bd[v];
    const ushort* rp = rs + rr * 1024;
#pragma unroll 8
    for (int k = 0; k < 1024; k++) acc += bf2f(rp[k]) * wd[(size_t)k * V + v];
    const int row = r0 + rr, pos = row >> 5, b = row & 31;
    out[((size_t)b * TT + pos) * V + v] = acc;
  }
}

// ---------------- host ----------------
extern "C" void kernel_launch(void* const* d_in, const int* in_sizes, int n_in,
                              void* d_out, int out_size, void* d_ws, size_t ws_size,
                              hipStream_t stream) {
  const float* x      = (const float*)d_in[0];
  const float* conv_w = (const float*)d_in[1];
  const float* conv_b = (const float*)d_in[2];
  const float* wi1f = (const float*)d_in[3];
  const float* wh1f = (const float*)d_in[4];
  const float* b1f  = (const float*)d_in[5];
  const float* wi1b = (const float*)d_in[6];
  const float* wh1b = (const float*)d_in[7];
  const float* b1b  = (const float*)d_in[8];
  const float* wi2f = (const float*)d_in[9];
  const float* wh2f = (const float*)d_in[10];
  const float* b2f  = (const float*)d_in[11];
  const float* wi2b = (const float*)d_in[12];
  const float* wh2b = (const float*)d_in[13];
  const float* b2b  = (const float*)d_in[14];
  const float* wd   = (const float*)d_in[15];
  const float* bd   = (const float*)d_in[16];
  float* out = (float*)d_out;

  char* ws = (char*)d_ws;
  size_t o = 0;
  auto alloc = [&](size_t sz) { size_t r = o; o = (o + sz + 255) & ~(size_t)255; return r; };
  const size_t oH2  = alloc((size_t)MROWS * 1024 * 2);  // 65.5MB; Y overlays first 16.4MB
  const size_t oY   = oH2;                              // conv out, dead before rec2 writes H2
  const size_t oXGF = alloc((size_t)CROWS * G4 * 2);    // 13.1MB chunk buffer (also im2col scratch)
  const size_t oXGB = alloc((size_t)CROWS * G4 * 2);
  const size_t oH1  = alloc((size_t)MROWS * 1024 * 2);
  const size_t oCW  = alloc((size_t)F * KC * 2);
  const size_t oW1F = alloc((size_t)G4 * F * 2);
  const size_t oW1B = alloc((size_t)G4 * F * 2);
  const size_t oW2F = alloc((size_t)G4 * 1024 * 2);
  const size_t oW2B = alloc((size_t)G4 * 1024 * 2);
  const size_t oR1  = alloc((size_t)(1 << 21) * 2);
  const size_t oR2  = alloc((size_t)(1 << 21) * 2);
  const size_t oCST = alloc((size_t)8 * 512 * 32 * 4);
  if (ws_size < o) return;  // workspace insufficient (~177MB needed)

  ushort* H2  = (ushort*)(ws + oH2);
  ushort* Y   = (ushort*)(ws + oY);
  ushort* XGF = (ushort*)(ws + oXGF);
  ushort* XGB = (ushort*)(ws + oXGB);
  ushort* H1  = (ushort*)(ws + oH1);
  ushort* CW  = (ushort*)(ws + oCW);
  ushort* W1F = (ushort*)(ws + oW1F);
  ushort* W1B = (ushort*)(ws + oW1B);
  ushort* W2F = (ushort*)(ws + oW2F);
  ushort* W2B = (ushort*)(ws + oW2B);
  ushort* R1  = (ushort*)(ws + oR1);
  ushort* R2  = (ushort*)(ws + oR2);
  float*  CST = (float*)(ws + oCST);

  const int N8 = MROWS * 1024 / 8;  // uint4 count for one h buffer
  hipLaunchKernelGGL(k_fillsent, dim3((N8 + 255) / 256), dim3(256), 0, stream, (uint4*)H1, N8);
  hipLaunchKernelGGL(k_convw, dim3((F * KC + 255) / 256), dim3(256), 0, stream, conv_w, CW);
  hipLaunchKernelGGL(k_transp, dim3((F * G4 + 255) / 256), dim3(256), 0, stream, wi1f, W1F, F, G4);
  hipLaunchKernelGGL(k_transp, dim3((F * G4 + 255) / 256), dim3(256), 0, stream, wi1b, W1B, F, G4);
  hipLaunchKernelGGL(k_transp, dim3((1024 * G4 + 255) / 256), dim3(256), 0, stream, wi2f, W2F, 1024, G4);
  hipLaunchKernelGGL(k_transp, dim3((1024 * G4 + 255) / 256), dim3(256), 0, stream, wi2b, W2B, 1024, G4);
  hipLaunchKernelGGL(k_whr, dim3((1 << 21) / 256), dim3(256), 0, stream, wh1f, wh1b, R1);
  hipLaunchKernelGGL(k_whr, dim3((1 << 21) / 256), dim3(256), 0, stream, wh2f, wh2b, R2);

  // conv as chunked im2col + GEMM (+bias+relu) -> Y bf16 [32000,256] (row-major)
  for (int p = 0; p < NCH; ++p) {
    hipLaunchKernelGGL(k_im2col, dim3((CROWS * KC + 255) / 256), dim3(256), 0, stream,
                       x, XGF, p * CH);
    hipLaunchKernelGGL(k_gemm, dim3(CROWS / 128, F / 128), dim3(256), 0, stream,
                       XGF, CW, conv_b, Y + (size_t)p * CROWS * F, F, KC, 1, 0);
  }
  // layer 1: chunked projections (transposed xg) + recurrence -> H1 [1000][32][1024]
  for (int p = 0; p < NCH; ++p) {
    hipLaunchKernelGGL(k_gemm, dim3(CROWS / 128, G4 / 128), dim3(256), 0, stream,
                       Y + (size_t)p * CROWS * F, W1F, b1f, XGF, G4, F, 0, 1);
    hipLaunchKernelGGL(k_gemm, dim3(CROWS / 128, G4 / 128), dim3(256), 0, stream,
                       Y + (size_t)(NCH - 1 - p) * CROWS * F, W1B, b1b, XGB, G4, F, 0, 1);
    hipLaunchKernelGGL(k_rec, dim3(8), dim3(512), 0, stream, XGF, XGB, R1, H1, CST, p * CH);
  }
  // sentinel-fill H2 now that Y (overlaid) is fully consumed, before layer-2 recurrence
  hipLaunchKernelGGL(k_fillsent, dim3((N8 + 255) / 256), dim3(256), 0, stream, (uint4*)H2, N8);
  // layer 2: chunked projections + recurrence -> H2
  for (int p = 0; p < NCH; ++p) {
    hipLaunchKernelGGL(k_gemm, dim3(CROWS / 128, G4 / 128), dim3(256), 0, stream,
                       H1 + (size_t)p * CROWS * 1024, W2F, b2f, XGF, G4, 1024, 0, 1);
    hipLaunchKernelGGL(k_gemm, dim3(CROWS / 128, G4 / 128), dim3(256), 0, stream,
                       H1 + (size_t)(NCH - 1 - p) * CROWS * 1024, W2B, b2b, XGB, G4, 1024, 0, 1);
    hipLaunchKernelGGL(k_rec, dim3(8), dim3(512), 0, stream, XGF, XGB, R2, H2, CST, p * CH);
  }
  // dense
  hipLaunchKernelGGL(k_dense, dim3(MROWS / 8), dim3(256), 0, stream, H2, wd, bd, out);
}

// Round 11
// 21751.558 us; speedup vs baseline: 2.3251x; 2.3251x over previous
//
#include <hip/hip_runtime.h>

// ---------------- constants ----------------
static constexpr int BB = 32, TI = 2000, TT = 1000, CIN = 80, F = 256, KW = 11;
static constexpr int G4 = 2048, V = 29;
static constexpr int MROWS = TT * BB;   // 32000
static constexpr int KC = 896;          // conv K (11*80=880) padded to mult of 64
static constexpr int CH = 100;          // steps per recurrence chunk
static constexpr int NCH = TT / CH;     // 10 chunks
static constexpr int CROWS = CH * BB;   // 3200 rows per chunk
static constexpr unsigned SENT = 0x7FC0u;            // bf16 NaN: h can never produce it
static constexpr unsigned SENT2 = 0x7FC07FC0u;

using short8 = __attribute__((ext_vector_type(8))) short;
using f32x4  = __attribute__((ext_vector_type(4))) float;
using u32x4  = __attribute__((ext_vector_type(4))) unsigned int;  // asm-friendly 128-bit

#define DEV __device__ __forceinline__

DEV ushort f2bf(float f) {
  unsigned u = __float_as_uint(f);
  unsigned r = (u + 0x7FFFu + ((u >> 16) & 1u)) >> 16;
  return (ushort)r;
}
DEV float bf2f(ushort h) { return __uint_as_float(((unsigned)h) << 16); }
DEV float sigm(float x) { return 1.f / (1.f + __expf(-x)); }
DEV float tanhft(float x) { return 1.f - 2.f / (__expf(2.f * x) + 1.f); }

// device-scope (MALL-coherent, sc1) wide ops for cross-block h exchange
DEV void ld64_sc1(const u32x4* p, u32x4* v) {
  asm volatile(
      "global_load_dwordx4 %0, %[a], off sc1\n\t"
      "global_load_dwordx4 %1, %[a], off offset:16 sc1\n\t"
      "global_load_dwordx4 %2, %[a], off offset:32 sc1\n\t"
      "global_load_dwordx4 %3, %[a], off offset:48 sc1\n\t"
      "s_waitcnt vmcnt(0)"
      : "=&v"(v[0]), "=&v"(v[1]), "=&v"(v[2]), "=&v"(v[3])
      : [a] "v"(p)
      : "memory");
}
DEV void st16_sc1(u32x4* p, u32x4 v) {
  asm volatile("global_store_dwordx4 %0, %1, off sc1" :: "v"(p), "v"(v) : "memory");
}

// any 16-bit half equals sentinel?
DEV int anysent(unsigned x) {
  unsigned y = x ^ SENT2;
  return ((y & 0xFFFFu) == 0u) | ((y >> 16) == 0u);
}
DEV int ok16(u32x4 v) {
  return !(anysent(v[0]) | anysent(v[1]) | anysent(v[2]) | anysent(v[3]));
}

// ---------------- prep kernels ----------------
// fill n8 * 8 ushorts with sentinel (uint4 = 8 bf16 per thread)
__global__ void k_fillsent(uint4* p, int n8) {
  int i = blockIdx.x * blockDim.x + threadIdx.x;
  if (i < n8) { uint4 s = {SENT2, SENT2, SENT2, SENT2}; p[i] = s; }
}

// conv_w [11][80][256] -> CW [256][896] bf16 (K padded w/ zeros)
__global__ void k_convw(const float* __restrict__ w, ushort* __restrict__ dst) {
  int idx = blockIdx.x * blockDim.x + threadIdx.x;
  if (idx >= F * KC) return;
  int f = idx / KC, kk = idx % KC;
  float v = (kk < KW * CIN) ? w[(size_t)kk * F + f] : 0.f;
  dst[idx] = f2bf(v);
}

// src [K][N] fp32 -> dst [N][K] bf16
__global__ void k_transp(const float* __restrict__ src, ushort* __restrict__ dst, int K, int N) {
  int idx = blockIdx.x * blockDim.x + threadIdx.x;
  if (idx >= K * N) return;
  int n = idx / K, k = idx % K;
  dst[idx] = f2bf(src[(size_t)k * N + n]);
}

// wh [512][2048] fp32 (f and b) -> packed MFMA B-fragments, 64-col-block layout.
// idx bits: j:0-2, lane:3-8, kk:9-12, cg:13, w:14-16, bpart:17-19, d:20
__global__ void k_whr(const float* __restrict__ whf, const float* __restrict__ whb,
                      ushort* __restrict__ dst) {
  int idx = blockIdx.x * blockDim.x + threadIdx.x;
  if (idx >= (1 << 21)) return;
  int j = idx & 7, lane = (idx >> 3) & 63, kk = (idx >> 9) & 15;
  int cg = (idx >> 13) & 1, w = (idx >> 14) & 7, bpart = (idx >> 17) & 7, d = (idx >> 20) & 1;
  int c16 = lane & 15, q = lane >> 4;
  int hc = bpart * 64 + w * 8 + cg * 4 + (c16 >> 2);
  int g = c16 & 3;
  int k = kk * 32 + q * 8 + j;
  int col = g * 512 + hc;
  const float* s = d ? whb : whf;
  dst[idx] = f2bf(s[(size_t)k * G4 + col]);
}

// x [32][2000][80] fp32 -> A0 [3200][896] bf16 im2col chunk (rows: (pos-pos0)*32+b)
__global__ void k_im2col(const float* __restrict__ x, ushort* __restrict__ A0, int pos0) {
  int idx = blockIdx.x * blockDim.x + threadIdx.x;
  if (idx >= CROWS * KC) return;
  int row = idx / KC, kk = idx % KC;
  int pos = pos0 + (row >> 5), b = row & 31;
  float v = 0.f;
  if (kk < KW * CIN) {
    int k = kk / CIN, c = kk % CIN;
    int tx = 2 * pos + k - 4;
    if (tx >= 0 && tx < TI) v = x[((size_t)b * TI + tx) * CIN + c];
  }
  A0[idx] = f2bf(v);
}

// ---------------- GEMM: C = A[.,K] * BT[N,K]^T + bias (bf16 in/out, fp32 acc) ----------
// grid (Mtiles, N/128). 128x128 tile, BK=64, 4 waves, 4x4 16x16 frags/wave.
// tmode=0: C[row*N+col] (optional relu). tmode=1: C[col*CROWS+row] packed 4-row stores.
__global__ __launch_bounds__(256, 2) void k_gemm(const ushort* __restrict__ A,
                                                 const ushort* __restrict__ BT,
                                                 const float* __restrict__ bias,
                                                 ushort* __restrict__ C,
                                                 int N, int K, int relu, int tmode) {
  __shared__ ushort As[128 * 64];
  __shared__ ushort Bs[128 * 64];
  const int tid = threadIdx.x;
  const int lane = tid & 63, wid = tid >> 6;
  const int wm = wid >> 1, wn = wid & 1;
  const int l16 = lane & 15, q = lane >> 4;
  const int bm = blockIdx.x, bn = blockIdx.y;
  const int srow = tid >> 1, scol = (tid & 1) * 32;
  const ushort* ga = A + (size_t)(bm * 128 + srow) * K + scol;
  const ushort* gb = BT + (size_t)(bn * 128 + srow) * K + scol;

  f32x4 acc[4][4] = {};
  uint4 va[4], vb[4];
#pragma unroll
  for (int i = 0; i < 4; i++) { va[i] = ((const uint4*)ga)[i]; vb[i] = ((const uint4*)gb)[i]; }

  for (int k0 = 0; k0 < K; k0 += 64) {
    __syncthreads();
#pragma unroll
    for (int i = 0; i < 4; i++) {
      *(uint4*)&As[srow * 64 + scol + i * 8] = va[i];
      *(uint4*)&Bs[srow * 64 + scol + i * 8] = vb[i];
    }
    __syncthreads();
    if (k0 + 64 < K) {
      const ushort* na = ga + k0 + 64;
      const ushort* nb = gb + k0 + 64;
#pragma unroll
      for (int i = 0; i < 4; i++) { va[i] = ((const uint4*)na)[i]; vb[i] = ((const uint4*)nb)[i]; }
    }
#pragma unroll
    for (int kk = 0; kk < 2; kk++) {
      short8 af[4], bf[4];
#pragma unroll
      for (int mt = 0; mt < 4; mt++)
        af[mt] = *(const short8*)&As[(wm * 64 + mt * 16 + l16) * 64 + kk * 32 + q * 8];
#pragma unroll
      for (int nt = 0; nt < 4; nt++)
        bf[nt] = *(const short8*)&Bs[(wn * 64 + nt * 16 + l16) * 64 + kk * 32 + q * 8];
#pragma unroll
      for (int mt = 0; mt < 4; mt++)
#pragma unroll
        for (int nt = 0; nt < 4; nt++)
          acc[mt][nt] = __builtin_amdgcn_mfma_f32_16x16x32_bf16(af[mt], bf[nt], acc[mt][nt], 0, 0, 0);
    }
  }
  if (tmode == 0) {
#pragma unroll
    for (int mt = 0; mt < 4; mt++) {
#pragma unroll
      for (int nt = 0; nt < 4; nt++) {
        int col = bn * 128 + wn * 64 + nt * 16 + l16;
        float bv = bias[col];
#pragma unroll
        for (int r = 0; r < 4; r++) {
          int row = bm * 128 + wm * 64 + mt * 16 + q * 4 + r;
          float v = acc[mt][nt][r] + bv;
          if (relu) v = fmaxf(v, 0.f);
          C[(size_t)row * N + col] = f2bf(v);
        }
      }
    }
  } else {
#pragma unroll
    for (int mt = 0; mt < 4; mt++) {
#pragma unroll
      for (int nt = 0; nt < 4; nt++) {
        int col = bn * 128 + wn * 64 + nt * 16 + l16;
        float bv = bias[col];
        ushort4 pk;
        pk.x = f2bf(acc[mt][nt][0] + bv);
        pk.y = f2bf(acc[mt][nt][1] + bv);
        pk.z = f2bf(acc[mt][nt][2] + bv);
        pk.w = f2bf(acc[mt][nt][3] + bv);
        int row = bm * 128 + wm * 64 + mt * 16 + q * 4;
        *(ushort4*)&C[(size_t)col * CROWS + row] = pk;
      }
    }
  }
}

// ---------------- persistent BiLSTM recurrence chunk (64-col blocks) ----------
// 16 blocks x 512 threads; block = d*8 + bpart: bpart owns h-cols [bpart*64, bpart*64+64).
// wf[2][16] = 128 regs of pre-packed B-fragments (fits 256-reg/wave cap at 2 waves/SIMD).
// Per wave per step: 64 MFMAs. Fan-in 8 (vs 16): lower max-of-N jitter, half poll traffic.
// Own slice read from LDS hstage (no global round-trip). Sentinel poll protocol (round 9).
__global__ __launch_bounds__(512, 1) void k_rec(const ushort* __restrict__ xgf,
                                                const ushort* __restrict__ xgb,
                                                const ushort* __restrict__ whr,
                                                ushort* __restrict__ hout,
                                                float* __restrict__ cstbuf,
                                                int s0) {
  __shared__ ushort hs[32 * 512];     // 32KB gather target, rows XOR-swizzled
  __shared__ ushort hstage[32 * 64];  // 4KB producer staging [row][local hcol]
  const int tid = threadIdx.x, lane = tid & 63, w = tid >> 6;
  const int bpart = blockIdx.x & 7, d = blockIdx.x >> 3;
  const int l16 = lane & 15, q = lane >> 4;
  const ushort* xg = d ? xgb : xgf;   // transposed layout [2048][CROWS]
  float* cs = cstbuf + ((size_t)blockIdx.x * 512 + tid) * 16;

  short8 wf[2][16];   // 128 regs: B-fragments for this block's 64 cols x 4 gates
  {
    const ushort* p = whr + ((size_t)((d * 8 + bpart) * 8 + w) * 2) * (16 * 512) + (size_t)lane * 8;
#pragma unroll
    for (int cg = 0; cg < 2; cg++)
#pragma unroll
      for (int kk = 0; kk < 16; kk++)
        wf[cg][kk] = *(const short8*)(p + ((size_t)cg * 16 + kk) * 512);
  }
  const int g = l16 & 3;
  const int hcb = bpart * 64 + w * 8 + (l16 >> 2);  // + cg*4 per col-group
  float cst[2][2][4];
#pragma unroll
  for (int cg = 0; cg < 2; cg++)
#pragma unroll
    for (int mt = 0; mt < 2; mt++)
#pragma unroll
      for (int r = 0; r < 4; r++)
        cst[cg][mt][r] = (s0 == 0) ? 0.f : cs[cg * 8 + mt * 4 + r];

  for (int ls = 0; ls < CH; ls++) {
    const int s = s0 + ls;
    const int pos = d ? (999 - s) : s;
    const int lp = d ? (CH - 1 - ls) : ls;    // local row block in xg chunk buffer
    // prefetch xt from transposed xg (independent of h -> overlaps poll latency)
    ushort4 xt[2][2];
#pragma unroll
    for (int cg = 0; cg < 2; cg++) {
      const ushort* xc = xg + (size_t)(g * 512 + hcb + cg * 4) * CROWS + lp * 32 + q * 4;
      xt[cg][0] = *(const ushort4*)(xc);        // rows q*4+0..3    (mt=0)
      xt[cg][1] = *(const ushort4*)(xc + 16);   // rows 16+q*4+0..3 (mt=1)
    }

    if (s == 0) {
      uint4 z4 = {0, 0, 0, 0};
#pragma unroll
      for (int i = 0; i < 4; i++) ((uint4*)hs)[tid * 4 + i] = z4;
    } else {
      // gather h_prev: wave w polls producer w; thread handles (row, 64B chunk cc)
      const int row = lane >> 1, cc = lane & 1;
      const int swz = (row & 7) << 4;
      char* L = (char*)hs + row * 1024;
      const int cb = w * 128 + cc * 64;
      u32x4 v[4];
      if (ls > 0 && w == bpart) {
        // own slice: hstage still holds step s-1 values (ordered by trailing barrier)
#pragma unroll
        for (int k = 0; k < 4; k++)
          v[k] = *(const u32x4*)((char*)hstage + row * 128 + cc * 64 + k * 16);
      } else {
        const int ppos = d ? pos + 1 : pos - 1;
        const u32x4* gb = (const u32x4*)(hout + ((size_t)ppos * 32 + row) * 1024 +
                                         d * 512 + w * 64 + cc * 32);
        do {
          ld64_sc1(gb, v);
        } while (__any(!(ok16(v[0]) & ok16(v[1]) & ok16(v[2]) & ok16(v[3]))));
      }
#pragma unroll
      for (int k = 0; k < 4; k++)
        *(u32x4*)(L + ((cb + k * 16) ^ swz)) = v[k];
    }
    __syncthreads();

    f32x4 za[2][2] = {};
#pragma unroll
    for (int kk = 0; kk < 16; kk++) {
      short8 a[2];
#pragma unroll
      for (int mt = 0; mt < 2; mt++) {
        int row = mt * 16 + l16;
        int cb = kk * 64 + q * 16;
        a[mt] = *(const short8*)((char*)hs + row * 1024 + (cb ^ ((row & 7) << 4)));
      }
#pragma unroll
      for (int mt = 0; mt < 2; mt++)
#pragma unroll
        for (int cg = 0; cg < 2; cg++)
          za[mt][cg] = __builtin_amdgcn_mfma_f32_16x16x32_bf16(a[mt], wf[cg][kk], za[mt][cg], 0, 0, 0);
    }

#pragma unroll
    for (int cg = 0; cg < 2; cg++)
#pragma unroll
      for (int mt = 0; mt < 2; mt++)
#pragma unroll
        for (int r = 0; r < 4; r++) {
          int bt = mt * 16 + q * 4 + r;
          ushort xr = (r == 0) ? xt[cg][mt].x : (r == 1) ? xt[cg][mt].y
                     : (r == 2) ? xt[cg][mt].z : xt[cg][mt].w;
          float z = za[mt][cg][r] + bf2f(xr);
          int base = lane & ~3;
          float zi = __shfl(z, base + 0);
          float zf = __shfl(z, base + 1);
          float zg = __shfl(z, base + 2);
          float zo = __shfl(z, base + 3);
          float cn = sigm(zf) * cst[cg][mt][r] + sigm(zi) * tanhft(zg);
          cst[cg][mt][r] = cn;
          float hv = sigm(zo) * tanhft(cn);
          if (g == 0) hstage[bt * 64 + w * 8 + cg * 4 + (l16 >> 2)] = f2bf(hv);
        }
    __syncthreads();  // hstage complete (also orders prior LDS reads before overwrite)
    // coalesced producer store: 256 threads x 16B = 4KB slice, sc1 fire-and-forget
    if (tid < 256) {
      const int row = tid >> 3, ck = tid & 7;
      u32x4 dv = *(u32x4*)((char*)hstage + row * 128 + ck * 16);
      st16_sc1((u32x4*)(hout + ((size_t)pos * 32 + row) * 1024 + d * 512 + bpart * 64) + ck, dv);
    }
  }
#pragma unroll
  for (int cg = 0; cg < 2; cg++)
#pragma unroll
    for (int mt = 0; mt < 2; mt++)
#pragma unroll
      for (int r = 0; r < 4; r++) cs[cg * 8 + mt * 4 + r] = cst[cg][mt][r];
}

// ---------------- dense: out[b][pos][29] = h2[row,1024] . W[1024,29] + bias ------------
__global__ __launch_bounds__(256, 2) void k_dense(const ushort* __restrict__ h2,
                                                  const float* __restrict__ wd,
                                                  const float* __restrict__ bd,
                                                  float* __restrict__ out) {
  __shared__ ushort rs[8 * 1024];
  const int tid = threadIdx.x;
  const int r0 = blockIdx.x * 8;
  const uint4* src = (const uint4*)(h2 + (size_t)r0 * 1024);
#pragma unroll
  for (int i = 0; i < 4; i++) ((uint4*)rs)[tid * 4 + i] = src[tid * 4 + i];
  __syncthreads();
  if (tid < 8 * V) {
    const int rr = tid / V, v = tid % V;
    float acc = bd[v];
    const ushort* rp = rs + rr * 1024;
#pragma unroll 8
    for (int k = 0; k < 1024; k++) acc += bf2f(rp[k]) * wd[(size_t)k * V + v];
    const int row = r0 + rr, pos = row >> 5, b = row & 31;
    out[((size_t)b * TT + pos) * V + v] = acc;
  }
}

// ---------------- host ----------------
extern "C" void kernel_launch(void* const* d_in, const int* in_sizes, int n_in,
                              void* d_out, int out_size, void* d_ws, size_t ws_size,
                              hipStream_t stream) {
  const float* x      = (const float*)d_in[0];
  const float* conv_w = (const float*)d_in[1];
  const float* conv_b = (const float*)d_in[2];
  const float* wi1f = (const float*)d_in[3];
  const float* wh1f = (const float*)d_in[4];
  const float* b1f  = (const float*)d_in[5];
  const float* wi1b = (const float*)d_in[6];
  const float* wh1b = (const float*)d_in[7];
  const float* b1b  = (const float*)d_in[8];
  const float* wi2f = (const float*)d_in[9];
  const float* wh2f = (const float*)d_in[10];
  const float* b2f  = (const float*)d_in[11];
  const float* wi2b = (const float*)d_in[12];
  const float* wh2b = (const float*)d_in[13];
  const float* b2b  = (const float*)d_in[14];
  const float* wd   = (const float*)d_in[15];
  const float* bd   = (const float*)d_in[16];
  float* out = (float*)d_out;

  char* ws = (char*)d_ws;
  size_t o = 0;
  auto alloc = [&](size_t sz) { size_t r = o; o = (o + sz + 255) & ~(size_t)255; return r; };
  const size_t oH2  = alloc((size_t)MROWS * 1024 * 2);  // 65.5MB; Y overlays first 16.4MB
  const size_t oY   = oH2;                              // conv out, dead before rec2 writes H2
  const size_t oXGF = alloc((size_t)CROWS * G4 * 2);    // 13.1MB chunk buffer (also im2col scratch)
  const size_t oXGB = alloc((size_t)CROWS * G4 * 2);
  const size_t oH1  = alloc((size_t)MROWS * 1024 * 2);
  const size_t oCW  = alloc((size_t)F * KC * 2);
  const size_t oW1F = alloc((size_t)G4 * F * 2);
  const size_t oW1B = alloc((size_t)G4 * F * 2);
  const size_t oW2F = alloc((size_t)G4 * 1024 * 2);
  const size_t oW2B = alloc((size_t)G4 * 1024 * 2);
  const size_t oR1  = alloc((size_t)(1 << 21) * 2);
  const size_t oR2  = alloc((size_t)(1 << 21) * 2);
  const size_t oCST = alloc((size_t)16 * 512 * 16 * 4);
  if (ws_size < o) return;  // workspace insufficient (~177MB needed)

  ushort* H2  = (ushort*)(ws + oH2);
  ushort* Y   = (ushort*)(ws + oY);
  ushort* XGF = (ushort*)(ws + oXGF);
  ushort* XGB = (ushort*)(ws + oXGB);
  ushort* H1  = (ushort*)(ws + oH1);
  ushort* CW  = (ushort*)(ws + oCW);
  ushort* W1F = (ushort*)(ws + oW1F);
  ushort* W1B = (ushort*)(ws + oW1B);
  ushort* W2F = (ushort*)(ws + oW2F);
  ushort* W2B = (ushort*)(ws + oW2B);
  ushort* R1  = (ushort*)(ws + oR1);
  ushort* R2  = (ushort*)(ws + oR2);
  float*  CST = (float*)(ws + oCST);

  const int N8 = MROWS * 1024 / 8;  // uint4 count for one h buffer
  hipLaunchKernelGGL(k_fillsent, dim3((N8 + 255) / 256), dim3(256), 0, stream, (uint4*)H1, N8);
  hipLaunchKernelGGL(k_convw, dim3((F * KC + 255) / 256), dim3(256), 0, stream, conv_w, CW);
  hipLaunchKernelGGL(k_transp, dim3((F * G4 + 255) / 256), dim3(256), 0, stream, wi1f, W1F, F, G4);
  hipLaunchKernelGGL(k_transp, dim3((F * G4 + 255) / 256), dim3(256), 0, stream, wi1b, W1B, F, G4);
  hipLaunchKernelGGL(k_transp, dim3((1024 * G4 + 255) / 256), dim3(256), 0, stream, wi2f, W2F, 1024, G4);
  hipLaunchKernelGGL(k_transp, dim3((1024 * G4 + 255) / 256), dim3(256), 0, stream, wi2b, W2B, 1024, G4);
  hipLaunchKernelGGL(k_whr, dim3((1 << 21) / 256), dim3(256), 0, stream, wh1f, wh1b, R1);
  hipLaunchKernelGGL(k_whr, dim3((1 << 21) / 256), dim3(256), 0, stream, wh2f, wh2b, R2);

  // conv as chunked im2col + GEMM (+bias+relu) -> Y bf16 [32000,256] (row-major)
  for (int p = 0; p < NCH; ++p) {
    hipLaunchKernelGGL(k_im2col, dim3((CROWS * KC + 255) / 256), dim3(256), 0, stream,
                       x, XGF, p * CH);
    hipLaunchKernelGGL(k_gemm, dim3(CROWS / 128, F / 128), dim3(256), 0, stream,
                       XGF, CW, conv_b, Y + (size_t)p * CROWS * F, F, KC, 1, 0);
  }
  // layer 1: chunked projections (transposed xg) + recurrence -> H1 [1000][32][1024]
  for (int p = 0; p < NCH; ++p) {
    hipLaunchKernelGGL(k_gemm, dim3(CROWS / 128, G4 / 128), dim3(256), 0, stream,
                       Y + (size_t)p * CROWS * F, W1F, b1f, XGF, G4, F, 0, 1);
    hipLaunchKernelGGL(k_gemm, dim3(CROWS / 128, G4 / 128), dim3(256), 0, stream,
                       Y + (size_t)(NCH - 1 - p) * CROWS * F, W1B, b1b, XGB, G4, F, 0, 1);
    hipLaunchKernelGGL(k_rec, dim3(16), dim3(512), 0, stream, XGF, XGB, R1, H1, CST, p * CH);
  }
  // sentinel-fill H2 now that Y (overlaid) is fully consumed, before layer-2 recurrence
  hipLaunchKernelGGL(k_fillsent, dim3((N8 + 255) / 256), dim3(256), 0, stream, (uint4*)H2, N8);
  // layer 2: chunked projections + recurrence -> H2
  for (int p = 0; p < NCH; ++p) {
    hipLaunchKernelGGL(k_gemm, dim3(CROWS / 128, G4 / 128), dim3(256), 0, stream,
                       H1 + (size_t)p * CROWS * 1024, W2F, b2f, XGF, G4, 1024, 0, 1);
    hipLaunchKernelGGL(k_gemm, dim3(CROWS / 128, G4 / 128), dim3(256), 0, stream,
                       H1 + (size_t)(NCH - 1 - p) * CROWS * 1024, W2B, b2b, XGB, G4, 1024, 0, 1);
    hipLaunchKernelGGL(k_rec, dim3(16), dim3(512), 0, stream, XGF, XGB, R2, H2, CST, p * CH);
  }
  // dense
  hipLaunchKernelGGL(k_dense, dim3(MROWS / 8), dim3(256), 0, stream, H2, wd, bd, out);
}

// Round 12
// 12818.906 us; speedup vs baseline: 3.9454x; 1.6968x over previous
//
#include <hip/hip_runtime.h>

// ---------------- constants ----------------
static constexpr int BB = 32, TI = 2000, TT = 1000, CIN = 80, F = 256, KW = 11;
static constexpr int G4 = 2048, V = 29;
static constexpr int MROWS = TT * BB;   // 32000
static constexpr int KC = 896;          // conv K (11*80=880) padded to mult of 64
static constexpr int CH = 100;          // steps per recurrence chunk
static constexpr int NCH = TT / CH;     // 10 chunks
static constexpr int CROWS = CH * BB;   // 3200 rows per chunk
static constexpr unsigned SENT2 = 0x7FC07FC0u;       // bf16 NaN pair: h can never produce it
static constexpr int GEMM_BLKS = 224;                // fused-gemm blocks in k_recf
static constexpr int PROJ_JOBS = 2 * (CROWS / 128) * (G4 / 128);  // 800

using short8 = __attribute__((ext_vector_type(8))) short;
using f32x4  = __attribute__((ext_vector_type(4))) float;
using u32x4  = __attribute__((ext_vector_type(4))) unsigned int;  // asm-friendly 128-bit

#define DEV __device__ __forceinline__

DEV ushort f2bf(float f) {
  unsigned u = __float_as_uint(f);
  unsigned r = (u + 0x7FFFu + ((u >> 16) & 1u)) >> 16;
  return (ushort)r;
}
DEV float bf2f(ushort h) { return __uint_as_float(((unsigned)h) << 16); }
DEV float sigm(float x) { return 1.f / (1.f + __expf(-x)); }
DEV float tanhft(float x) { return 1.f - 2.f / (__expf(2.f * x) + 1.f); }

// device-scope (MALL-coherent, sc1) wide ops for cross-block h exchange
DEV void ld64_sc1(const u32x4* p, u32x4* v) {
  asm volatile(
      "global_load_dwordx4 %0, %[a], off sc1\n\t"
      "global_load_dwordx4 %1, %[a], off offset:16 sc1\n\t"
      "global_load_dwordx4 %2, %[a], off offset:32 sc1\n\t"
      "global_load_dwordx4 %3, %[a], off offset:48 sc1\n\t"
      "s_waitcnt vmcnt(0)"
      : "=&v"(v[0]), "=&v"(v[1]), "=&v"(v[2]), "=&v"(v[3])
      : [a] "v"(p)
      : "memory");
}
DEV void st16_sc1(u32x4* p, u32x4 v) {
  asm volatile("global_store_dwordx4 %0, %1, off sc1" :: "v"(p), "v"(v) : "memory");
}

DEV int anysent(unsigned x) {
  unsigned y = x ^ SENT2;
  return ((y & 0xFFFFu) == 0u) | ((y >> 16) == 0u);
}
DEV int ok16(u32x4 v) {
  return !(anysent(v[0]) | anysent(v[1]) | anysent(v[2]) | anysent(v[3]));
}

// ---------------- prep kernels ----------------
__global__ void k_fillsent(uint4* p, int n8) {
  int i = blockIdx.x * blockDim.x + threadIdx.x;
  if (i < n8) { uint4 s = {SENT2, SENT2, SENT2, SENT2}; p[i] = s; }
}

// conv_w [11][80][256] -> CW [256][896] bf16 (K padded w/ zeros)
__global__ void k_convw(const float* __restrict__ w, ushort* __restrict__ dst) {
  int idx = blockIdx.x * blockDim.x + threadIdx.x;
  if (idx >= F * KC) return;
  int f = idx / KC, kk = idx % KC;
  float v = (kk < KW * CIN) ? w[(size_t)kk * F + f] : 0.f;
  dst[idx] = f2bf(v);
}

// src [K][N] fp32 -> dst [N][K] bf16
__global__ void k_transp(const float* __restrict__ src, ushort* __restrict__ dst, int K, int N) {
  int idx = blockIdx.x * blockDim.x + threadIdx.x;
  if (idx >= K * N) return;
  int n = idx / K, k = idx % K;
  dst[idx] = f2bf(src[(size_t)k * N + n]);
}

// wh [512][2048] fp32 (f and b) -> packed MFMA B-fragments (round-9 32-col layout).
// linear idx = ((((d*16+part)*8+w)*16+kk)*64+lane)*8 + j
__global__ void k_whr(const float* __restrict__ whf, const float* __restrict__ whb,
                      ushort* __restrict__ dst) {
  int idx = blockIdx.x * blockDim.x + threadIdx.x;
  if (idx >= (1 << 21)) return;
  int j = idx & 7, lane = (idx >> 3) & 63, kk = (idx >> 9) & 15;
  int w = (idx >> 13) & 7, part = (idx >> 16) & 15, d = (idx >> 20) & 1;
  int c16 = lane & 15, q = lane >> 4;
  int jj = w * 4 + (c16 >> 2), g = c16 & 3;
  int k = kk * 32 + q * 8 + j;
  int col = g * 512 + part * 32 + jj;
  const float* s = d ? whb : whf;
  dst[idx] = f2bf(s[(size_t)k * G4 + col]);
}

// x [32][2000][80] fp32 -> A0 [3200][896] bf16 im2col chunk (rows: (pos-pos0)*32+b)
__global__ void k_im2col(const float* __restrict__ x, ushort* __restrict__ A0, int pos0) {
  int idx = blockIdx.x * blockDim.x + threadIdx.x;
  if (idx >= CROWS * KC) return;
  int row = idx / KC, kk = idx % KC;
  int pos = pos0 + (row >> 5), b = row & 31;
  float v = 0.f;
  if (kk < KW * CIN) {
    int k = kk / CIN, c = kk % CIN;
    int tx = 2 * pos + k - 4;
    if (tx >= 0 && tx < TI) v = x[((size_t)b * TI + tx) * CIN + c];
  }
  A0[idx] = f2bf(v);
}

// ---------------- standalone GEMM (256 thr): conv + first-chunk projections + fallback ----
__global__ __launch_bounds__(256, 2) void k_gemm(const ushort* __restrict__ A,
                                                 const ushort* __restrict__ BT,
                                                 const float* __restrict__ bias,
                                                 ushort* __restrict__ C,
                                                 int N, int K, int relu, int tmode) {
  __shared__ ushort As[128 * 64];
  __shared__ ushort Bs[128 * 64];
  const int tid = threadIdx.x;
  const int lane = tid & 63, wid = tid >> 6;
  const int wm = wid >> 1, wn = wid & 1;
  const int l16 = lane & 15, q = lane >> 4;
  const int bm = blockIdx.x, bn = blockIdx.y;
  const int srow = tid >> 1, scol = (tid & 1) * 32;
  const ushort* ga = A + (size_t)(bm * 128 + srow) * K + scol;
  const ushort* gb = BT + (size_t)(bn * 128 + srow) * K + scol;

  f32x4 acc[4][4] = {};
  uint4 va[4], vb[4];
#pragma unroll
  for (int i = 0; i < 4; i++) { va[i] = ((const uint4*)ga)[i]; vb[i] = ((const uint4*)gb)[i]; }

  for (int k0 = 0; k0 < K; k0 += 64) {
    __syncthreads();
#pragma unroll
    for (int i = 0; i < 4; i++) {
      *(uint4*)&As[srow * 64 + scol + i * 8] = va[i];
      *(uint4*)&Bs[srow * 64 + scol + i * 8] = vb[i];
    }
    __syncthreads();
    if (k0 + 64 < K) {
      const ushort* na = ga + k0 + 64;
      const ushort* nb = gb + k0 + 64;
#pragma unroll
      for (int i = 0; i < 4; i++) { va[i] = ((const uint4*)na)[i]; vb[i] = ((const uint4*)nb)[i]; }
    }
#pragma unroll
    for (int kk = 0; kk < 2; kk++) {
      short8 af[4], bf[4];
#pragma unroll
      for (int mt = 0; mt < 4; mt++)
        af[mt] = *(const short8*)&As[(wm * 64 + mt * 16 + l16) * 64 + kk * 32 + q * 8];
#pragma unroll
      for (int nt = 0; nt < 4; nt++)
        bf[nt] = *(const short8*)&Bs[(wn * 64 + nt * 16 + l16) * 64 + kk * 32 + q * 8];
#pragma unroll
      for (int mt = 0; mt < 4; mt++)
#pragma unroll
        for (int nt = 0; nt < 4; nt++)
          acc[mt][nt] = __builtin_amdgcn_mfma_f32_16x16x32_bf16(af[mt], bf[nt], acc[mt][nt], 0, 0, 0);
    }
  }
  if (tmode == 0) {
#pragma unroll
    for (int mt = 0; mt < 4; mt++) {
#pragma unroll
      for (int nt = 0; nt < 4; nt++) {
        int col = bn * 128 + wn * 64 + nt * 16 + l16;
        float bv = bias[col];
#pragma unroll
        for (int r = 0; r < 4; r++) {
          int row = bm * 128 + wm * 64 + mt * 16 + q * 4 + r;
          float v = acc[mt][nt][r] + bv;
          if (relu) v = fmaxf(v, 0.f);
          C[(size_t)row * N + col] = f2bf(v);
        }
      }
    }
  } else {
#pragma unroll
    for (int mt = 0; mt < 4; mt++) {
#pragma unroll
      for (int nt = 0; nt < 4; nt++) {
        int col = bn * 128 + wn * 64 + nt * 16 + l16;
        float bv = bias[col];
        ushort4 pk;
        pk.x = f2bf(acc[mt][nt][0] + bv);
        pk.y = f2bf(acc[mt][nt][1] + bv);
        pk.z = f2bf(acc[mt][nt][2] + bv);
        pk.w = f2bf(acc[mt][nt][3] + bv);
        int row = bm * 128 + wm * 64 + mt * 16 + q * 4;
        *(ushort4*)&C[(size_t)col * CROWS + row] = pk;
      }
    }
  }
}

// ---------------- fused gemm tile (512 thr, waves 0-3 active; barriers block-wide) -------
DEV void gemm_tile512(const ushort* __restrict__ A, const ushort* __restrict__ BT,
                      const float* __restrict__ bias, ushort* __restrict__ C,
                      int K, int bm, int bn, int tid, ushort* As, ushort* Bs) {
  const int lane = tid & 63, wid = tid >> 6;
  const bool act = wid < 4;
  const int wm = (wid >> 1) & 1, wn = wid & 1;
  const int l16 = lane & 15, q = lane >> 4;
  const int srow = (tid & 255) >> 1, scol = (tid & 1) * 32;
  const ushort* ga = A + (size_t)(bm * 128 + srow) * K + scol;
  const ushort* gb = BT + (size_t)(bn * 128 + srow) * K + scol;

  f32x4 acc[4][4] = {};
  uint4 va[4], vb[4];
  if (act) {
#pragma unroll
    for (int i = 0; i < 4; i++) { va[i] = ((const uint4*)ga)[i]; vb[i] = ((const uint4*)gb)[i]; }
  }
  for (int k0 = 0; k0 < K; k0 += 64) {
    __syncthreads();
    if (act) {
#pragma unroll
      for (int i = 0; i < 4; i++) {
        *(uint4*)&As[srow * 64 + scol + i * 8] = va[i];
        *(uint4*)&Bs[srow * 64 + scol + i * 8] = vb[i];
      }
    }
    __syncthreads();
    if (act) {
      if (k0 + 64 < K) {
        const ushort* na = ga + k0 + 64;
        const ushort* nb = gb + k0 + 64;
#pragma unroll
        for (int i = 0; i < 4; i++) { va[i] = ((const uint4*)na)[i]; vb[i] = ((const uint4*)nb)[i]; }
      }
#pragma unroll
      for (int kk = 0; kk < 2; kk++) {
        short8 af[4], bf[4];
#pragma unroll
        for (int mt = 0; mt < 4; mt++)
          af[mt] = *(const short8*)&As[(wm * 64 + mt * 16 + l16) * 64 + kk * 32 + q * 8];
#pragma unroll
        for (int nt = 0; nt < 4; nt++)
          bf[nt] = *(const short8*)&Bs[(wn * 64 + nt * 16 + l16) * 64 + kk * 32 + q * 8];
#pragma unroll
        for (int mt = 0; mt < 4; mt++)
#pragma unroll
          for (int nt = 0; nt < 4; nt++)
            acc[mt][nt] = __builtin_amdgcn_mfma_f32_16x16x32_bf16(af[mt], bf[nt], acc[mt][nt], 0, 0, 0);
      }
    }
  }
  if (act) {
#pragma unroll
    for (int mt = 0; mt < 4; mt++) {
#pragma unroll
      for (int nt = 0; nt < 4; nt++) {
        int col = bn * 128 + wn * 64 + nt * 16 + l16;
        float bv = bias[col];
        ushort4 pk;
        pk.x = f2bf(acc[mt][nt][0] + bv);
        pk.y = f2bf(acc[mt][nt][1] + bv);
        pk.z = f2bf(acc[mt][nt][2] + bv);
        pk.w = f2bf(acc[mt][nt][3] + bv);
        int row = bm * 128 + wm * 64 + mt * 16 + q * 4;
        *(ushort4*)&C[(size_t)col * CROWS + row] = pk;
      }
    }
  }
}

// ---------------- fused persistent rec + next-chunk projections ----------
// grid 256 x 512. Blocks 0-31: round-9 rec core (block=(d<<4)|part, 32 cols each,
// wf[16]=64 regs, sentinel poll, staged sc1 stores, own-slice LDS bypass).
// Blocks 32-255: grid-stride over njobs projection tiles for chunk p+1 (write other xg buf).
__global__ __launch_bounds__(512, 1) void k_recf(const ushort* __restrict__ xgf,
                                                 const ushort* __restrict__ xgb,
                                                 const ushort* __restrict__ whr,
                                                 ushort* __restrict__ hout,
                                                 float* __restrict__ cstbuf,
                                                 int s0,
                                                 const ushort* __restrict__ gAf,
                                                 const ushort* __restrict__ gAb,
                                                 const ushort* __restrict__ gBTf,
                                                 const ushort* __restrict__ gBTb,
                                                 const float* __restrict__ gbf,
                                                 const float* __restrict__ gbb,
                                                 ushort* __restrict__ gCf,
                                                 ushort* __restrict__ gCb,
                                                 int gK, int njobs) {
  __shared__ union SM {
    struct { ushort hs[32 * 512]; ushort hstage[32 * 32]; } r;  // 34KB rec
    struct { ushort As[128 * 64]; ushort Bs[128 * 64]; } g;     // 32KB gemm
  } sm;
  const int tid = threadIdx.x;

  if (blockIdx.x >= 32) {
    // ---- fused projection gemm blocks ----
    for (int job = (int)blockIdx.x - 32; job < njobs; job += GEMM_BLKS) {
      int dir = job / 400, t = job % 400, bm = t / 16, bn = t % 16;
      gemm_tile512(dir ? gAb : gAf, dir ? gBTb : gBTf, dir ? gbb : gbf, dir ? gCb : gCf,
                   gK, bm, bn, tid, sm.g.As, sm.g.Bs);
    }
    return;
  }

  // ---- rec core (round-9 structure) ----
  const int lane = tid & 63, w = tid >> 6;
  const int part = blockIdx.x & 15, d = blockIdx.x >> 4;
  const int l16 = lane & 15, q = lane >> 4;
  const ushort* xg = d ? xgb : xgf;   // transposed layout [2048][CROWS]
  float* cs = cstbuf + ((size_t)blockIdx.x * 512 + tid) * 8;

  short8 wf[16];
  {
    const ushort* p = whr + (((size_t)(d * 16 + part) * 8 + w) * 16 * 64 + lane) * 8;
#pragma unroll
    for (int kk = 0; kk < 16; kk++) wf[kk] = *(const short8*)(p + (size_t)kk * 64 * 8);
  }
  const int jj = w * 4 + (l16 >> 2), g = l16 & 3;
  const int gcol = g * 512 + part * 32 + jj;
  float cst[2][4];
#pragma unroll
  for (int mt = 0; mt < 2; mt++)
#pragma unroll
    for (int r = 0; r < 4; r++) cst[mt][r] = (s0 == 0) ? 0.f : cs[mt * 4 + r];

  for (int ls = 0; ls < CH; ls++) {
    const int s = s0 + ls;
    const int pos = d ? (999 - s) : s;
    const int lp = d ? (CH - 1 - ls) : ls;
    const ushort* xc = xg + (size_t)gcol * CROWS + lp * 32 + q * 4;
    ushort4 xt0 = *(const ushort4*)(xc);
    ushort4 xt1 = *(const ushort4*)(xc + 16);

    if (s == 0) {
      uint4 z4 = {0, 0, 0, 0};
#pragma unroll
      for (int i = 0; i < 4; i++) ((uint4*)sm.r.hs)[tid * 4 + i] = z4;
    } else {
      const int row = tid >> 4, p16 = tid & 15;
      u32x4 v[4];
      int own = (ls > 0) && (p16 == part);
      if (own) {
        // own slice: hstage still holds step s-1 values (LDS, no global round-trip)
#pragma unroll
        for (int k = 0; k < 4; k++)
          v[k] = *(const u32x4*)((char*)sm.r.hstage + row * 64 + k * 16);
      }
      const int ppos = d ? pos + 1 : pos - 1;
      const u32x4* gb = (const u32x4*)(hout + ((size_t)ppos * 32 + row) * 1024 +
                                       d * 512 + p16 * 32);
      int done = own;
      while (!__all(done)) {
        if (!done) {
          ld64_sc1(gb, v);
          done = ok16(v[0]) & ok16(v[1]) & ok16(v[2]) & ok16(v[3]);
        }
      }
      const int swz = (row & 7) << 4;
      char* L = (char*)sm.r.hs + row * 1024;
      const int cb = p16 * 64;
#pragma unroll
      for (int k = 0; k < 4; k++)
        *(u32x4*)(L + ((cb + k * 16) ^ swz)) = v[k];
    }
    __syncthreads();

    f32x4 za[2] = {};
#pragma unroll
    for (int kk = 0; kk < 16; kk++) {
#pragma unroll
      for (int mt = 0; mt < 2; mt++) {
        int row = mt * 16 + l16;
        int cb = kk * 64 + q * 16;
        short8 a = *(const short8*)((char*)sm.r.hs + row * 1024 + (cb ^ ((row & 7) << 4)));
        za[mt] = __builtin_amdgcn_mfma_f32_16x16x32_bf16(a, wf[kk], za[mt], 0, 0, 0);
      }
    }

#pragma unroll
    for (int mt = 0; mt < 2; mt++) {
#pragma unroll
      for (int r = 0; r < 4; r++) {
        int bt = mt * 16 + q * 4 + r;
        ushort xr = (mt == 0) ? ((r == 0) ? xt0.x : (r == 1) ? xt0.y : (r == 2) ? xt0.z : xt0.w)
                              : ((r == 0) ? xt1.x : (r == 1) ? xt1.y : (r == 2) ? xt1.z : xt1.w);
        float z = za[mt][r] + bf2f(xr);
        int base = lane & ~3;
        float zi = __shfl(z, base + 0);
        float zf = __shfl(z, base + 1);
        float zg = __shfl(z, base + 2);
        float zo = __shfl(z, base + 3);
        float cn = sigm(zf) * cst[mt][r] + sigm(zi) * tanhft(zg);
        cst[mt][r] = cn;
        float hv = sigm(zo) * tanhft(cn);
        if (g == 0) sm.r.hstage[bt * 32 + jj] = f2bf(hv);
      }
    }
    __syncthreads();  // hstage complete; hs free for next iteration
    // coalesced producer store: 128 threads x 16B = 2KB slice, sc1 fire-and-forget
    if ((lane & 12) == 0) {
      const int rr = 4 * w + (lane >> 4);
      const int ck = lane & 3;
      u32x4 dv = *(u32x4*)((char*)sm.r.hstage + rr * 64 + ck * 16);
      st16_sc1((u32x4*)(hout + ((size_t)pos * 32 + rr) * 1024 + d * 512 + part * 32) + ck, dv);
    }
  }
#pragma unroll
  for (int mt = 0; mt < 2; mt++)
#pragma unroll
    for (int r = 0; r < 4; r++) cs[mt * 4 + r] = cst[mt][r];
}

// ---------------- dense: out[b][pos][29] = h2[row,1024] . W[1024,29] + bias ------------
__global__ __launch_bounds__(256, 2) void k_dense(const ushort* __restrict__ h2,
                                                  const float* __restrict__ wd,
                                                  const float* __restrict__ bd,
                                                  float* __restrict__ out) {
  __shared__ ushort rs[8 * 1024];
  const int tid = threadIdx.x;
  const int r0 = blockIdx.x * 8;
  const uint4* src = (const uint4*)(h2 + (size_t)r0 * 1024);
#pragma unroll
  for (int i = 0; i < 4; i++) ((uint4*)rs)[tid * 4 + i] = src[tid * 4 + i];
  __syncthreads();
  if (tid < 8 * V) {
    const int rr = tid / V, v = tid % V;
    float acc = bd[v];
    const ushort* rp = rs + rr * 1024;
#pragma unroll 8
    for (int k = 0; k < 1024; k++) acc += bf2f(rp[k]) * wd[(size_t)k * V + v];
    const int row = r0 + rr, pos = row >> 5, b = row & 31;
    out[((size_t)b * TT + pos) * V + v] = acc;
  }
}

// ---------------- host ----------------
extern "C" void kernel_launch(void* const* d_in, const int* in_sizes, int n_in,
                              void* d_out, int out_size, void* d_ws, size_t ws_size,
                              hipStream_t stream) {
  const float* x      = (const float*)d_in[0];
  const float* conv_w = (const float*)d_in[1];
  const float* conv_b = (const float*)d_in[2];
  const float* wi1f = (const float*)d_in[3];
  const float* wh1f = (const float*)d_in[4];
  const float* b1f  = (const float*)d_in[5];
  const float* wi1b = (const float*)d_in[6];
  const float* wh1b = (const float*)d_in[7];
  const float* b1b  = (const float*)d_in[8];
  const float* wi2f = (const float*)d_in[9];
  const float* wh2f = (const float*)d_in[10];
  const float* b2f  = (const float*)d_in[11];
  const float* wi2b = (const float*)d_in[12];
  const float* wh2b = (const float*)d_in[13];
  const float* b2b  = (const float*)d_in[14];
  const float* wd   = (const float*)d_in[15];
  const float* bd   = (const float*)d_in[16];
  float* out = (float*)d_out;

  char* ws = (char*)d_ws;
  size_t o = 0;
  auto alloc = [&](size_t sz) { size_t r = o; o = (o + sz + 255) & ~(size_t)255; return r; };
  const size_t XG_SZ = (size_t)CROWS * G4 * 2;          // 13.1MB per xg buffer
  const size_t oH2  = alloc((size_t)MROWS * 1024 * 2);  // 65.5MB; Y overlays first 16.4MB
  const size_t oY   = oH2;
  const size_t oXGF0 = alloc(XG_SZ);
  const size_t oXGB0 = alloc(XG_SZ);
  const size_t oH1  = alloc((size_t)MROWS * 1024 * 2);
  const size_t oCW  = alloc((size_t)F * KC * 2);
  const size_t oW1F = alloc((size_t)G4 * F * 2);
  const size_t oW1B = alloc((size_t)G4 * F * 2);
  const size_t oW2F = alloc((size_t)G4 * 1024 * 2);
  const size_t oW2B = alloc((size_t)G4 * 1024 * 2);
  const size_t oR1  = alloc((size_t)(1 << 21) * 2);
  const size_t oR2  = alloc((size_t)(1 << 21) * 2);
  const size_t oCST = alloc((size_t)32 * 512 * 8 * 4);
  const size_t base_need = o;
  if (ws_size < base_need) return;
  // optional double-buffer for xg (enables fused next-chunk projections)
  size_t oXGF1 = oXGF0, oXGB1 = oXGB0;
  bool dbuf = false;
  {
    size_t o2 = o;
    size_t f1 = o2; o2 = (o2 + XG_SZ + 255) & ~(size_t)255;
    size_t b1 = o2; o2 = (o2 + XG_SZ + 255) & ~(size_t)255;
    if (ws_size >= o2) { dbuf = true; oXGF1 = f1; oXGB1 = b1; }
  }

  ushort* H2  = (ushort*)(ws + oH2);
  ushort* Y   = (ushort*)(ws + oY);
  ushort* XGF[2] = {(ushort*)(ws + oXGF0), (ushort*)(ws + oXGF1)};
  ushort* XGB[2] = {(ushort*)(ws + oXGB0), (ushort*)(ws + oXGB1)};
  ushort* H1  = (ushort*)(ws + oH1);
  ushort* CW  = (ushort*)(ws + oCW);
  ushort* W1F = (ushort*)(ws + oW1F);
  ushort* W1B = (ushort*)(ws + oW1B);
  ushort* W2F = (ushort*)(ws + oW2F);
  ushort* W2B = (ushort*)(ws + oW2B);
  ushort* R1  = (ushort*)(ws + oR1);
  ushort* R2  = (ushort*)(ws + oR2);
  float*  CST = (float*)(ws + oCST);

  const int N8 = MROWS * 1024 / 8;
  hipLaunchKernelGGL(k_fillsent, dim3((N8 + 255) / 256), dim3(256), 0, stream, (uint4*)H1, N8);
  hipLaunchKernelGGL(k_convw, dim3((F * KC + 255) / 256), dim3(256), 0, stream, conv_w, CW);
  hipLaunchKernelGGL(k_transp, dim3((F * G4 + 255) / 256), dim3(256), 0, stream, wi1f, W1F, F, G4);
  hipLaunchKernelGGL(k_transp, dim3((F * G4 + 255) / 256), dim3(256), 0, stream, wi1b, W1B, F, G4);
  hipLaunchKernelGGL(k_transp, dim3((1024 * G4 + 255) / 256), dim3(256), 0, stream, wi2f, W2F, 1024, G4);
  hipLaunchKernelGGL(k_transp, dim3((1024 * G4 + 255) / 256), dim3(256), 0, stream, wi2b, W2B, 1024, G4);
  hipLaunchKernelGGL(k_whr, dim3((1 << 21) / 256), dim3(256), 0, stream, wh1f, wh1b, R1);
  hipLaunchKernelGGL(k_whr, dim3((1 << 21) / 256), dim3(256), 0, stream, wh2f, wh2b, R2);

  // conv as chunked im2col + GEMM (+bias+relu) -> Y bf16 [32000,256] (row-major)
  for (int p = 0; p < NCH; ++p) {
    hipLaunchKernelGGL(k_im2col, dim3((CROWS * KC + 255) / 256), dim3(256), 0, stream,
                       x, XGF[0], p * CH);
    hipLaunchKernelGGL(k_gemm, dim3(CROWS / 128, F / 128), dim3(256), 0, stream,
                       XGF[0], CW, conv_b, Y + (size_t)p * CROWS * F, F, KC, 1, 0);
  }

  // ---- layer 1 ----
  hipLaunchKernelGGL(k_gemm, dim3(CROWS / 128, G4 / 128), dim3(256), 0, stream,
                     Y, W1F, b1f, XGF[0], G4, F, 0, 1);
  hipLaunchKernelGGL(k_gemm, dim3(CROWS / 128, G4 / 128), dim3(256), 0, stream,
                     Y + (size_t)9 * CROWS * F, W1B, b1b, XGB[0], G4, F, 0, 1);
  for (int p = 0; p < NCH; ++p) {
    const int q = p + 1;
    const bool fuse = dbuf && q < NCH;
    hipLaunchKernelGGL(k_recf, dim3(32 + GEMM_BLKS), dim3(512), 0, stream,
                       XGF[p & 1], XGB[p & 1], R1, H1, CST, p * CH,
                       fuse ? Y + (size_t)q * CROWS * F : (const ushort*)nullptr,
                       fuse ? Y + (size_t)(9 - q) * CROWS * F : (const ushort*)nullptr,
                       W1F, W1B, b1f, b1b,
                       XGF[q & 1], XGB[q & 1], F, fuse ? PROJ_JOBS : 0);
    if (!dbuf && q < NCH) {
      hipLaunchKernelGGL(k_gemm, dim3(CROWS / 128, G4 / 128), dim3(256), 0, stream,
                         Y + (size_t)q * CROWS * F, W1F, b1f, XGF[q & 1], G4, F, 0, 1);
      hipLaunchKernelGGL(k_gemm, dim3(CROWS / 128, G4 / 128), dim3(256), 0, stream,
                         Y + (size_t)(9 - q) * CROWS * F, W1B, b1b, XGB[q & 1], G4, F, 0, 1);
    }
  }

  // sentinel-fill H2 (Y dead: last proj1 consumer finished), before layer-2 recurrence
  hipLaunchKernelGGL(k_fillsent, dim3((N8 + 255) / 256), dim3(256), 0, stream, (uint4*)H2, N8);

  // ---- layer 2 ----
  hipLaunchKernelGGL(k_gemm, dim3(CROWS / 128, G4 / 128), dim3(256), 0, stream,
                     H1, W2F, b2f, XGF[0], G4, 1024, 0, 1);
  hipLaunchKernelGGL(k_gemm, dim3(CROWS / 128, G4 / 128), dim3(256), 0, stream,
                     H1 + (size_t)9 * CROWS * 1024, W2B, b2b, XGB[0], G4, 1024, 0, 1);
  for (int p = 0; p < NCH; ++p) {
    const int q = p + 1;
    const bool fuse = dbuf && q < NCH;
    hipLaunchKernelGGL(k_recf, dim3(32 + GEMM_BLKS), dim3(512), 0, stream,
                       XGF[p & 1], XGB[p & 1], R2, H2, CST, p * CH,
                       fuse ? H1 + (size_t)q * CROWS * 1024 : (const ushort*)nullptr,
                       fuse ? H1 + (size_t)(9 - q) * CROWS * 1024 : (const ushort*)nullptr,
                       W2F, W2B, b2f, b2b,
                       XGF[q & 1], XGB[q & 1], 1024, fuse ? PROJ_JOBS : 0);
    if (!dbuf && q < NCH) {
      hipLaunchKernelGGL(k_gemm, dim3(CROWS / 128, G4 / 128), dim3(256), 0, stream,
                         H1 + (size_t)q * CROWS * 1024, W2F, b2f, XGF[q & 1], G4, 1024, 0, 1);
      hipLaunchKernelGGL(k_gemm, dim3(CROWS / 128, G4 / 128), dim3(256), 0, stream,
                         H1 + (size_t)(9 - q) * CROWS * 1024, W2B, b2b, XGB[q & 1], G4, 1024, 0, 1);
    }
  }
  // dense
  hipLaunchKernelGGL(k_dense, dim3(MROWS / 8), dim3(256), 0, stream, H2, wd, bd, out);
}

// Round 13
// 12406.134 us; speedup vs baseline: 4.0766x; 1.0333x over previous
//
#include <hip/hip_runtime.h>

// ---------------- constants ----------------
static constexpr int BB = 32, TI = 2000, TT = 1000, CIN = 80, F = 256, KW = 11;
static constexpr int G4 = 2048, V = 29;
static constexpr int MROWS = TT * BB;   // 32000
static constexpr int KC = 896;          // conv K (11*80=880) padded to mult of 64
static constexpr int CH = 100;          // steps per recurrence chunk
static constexpr int NCH = TT / CH;     // 10 chunks
static constexpr int CROWS = CH * BB;   // 3200 rows per chunk
static constexpr unsigned SENT2 = 0x7FC07FC0u;       // bf16 NaN pair: h can never produce it
static constexpr int GEMM_BLKS = 224;                // fused-gemm blocks in k_recf
static constexpr int PROJ_JOBS = 2 * (CROWS / 128) * (G4 / 128);  // 800

using short8 = __attribute__((ext_vector_type(8))) short;
using f32x4  = __attribute__((ext_vector_type(4))) float;
using u32x4  = __attribute__((ext_vector_type(4))) unsigned int;  // asm-friendly 128-bit

#define DEV __device__ __forceinline__

DEV ushort f2bf(float f) {
  unsigned u = __float_as_uint(f);
  unsigned r = (u + 0x7FFFu + ((u >> 16) & 1u)) >> 16;
  return (ushort)r;
}
DEV float bf2f(ushort h) { return __uint_as_float(((unsigned)h) << 16); }
DEV float sigm(float x) { return 1.f / (1.f + __expf(-x)); }
DEV float tanhft(float x) { return 1.f - 2.f / (__expf(2.f * x) + 1.f); }

// device-scope (MALL-coherent, sc1) wide ops for cross-block h exchange
DEV void ld64_sc1(const u32x4* p, u32x4* v) {
  asm volatile(
      "global_load_dwordx4 %0, %[a], off sc1\n\t"
      "global_load_dwordx4 %1, %[a], off offset:16 sc1\n\t"
      "global_load_dwordx4 %2, %[a], off offset:32 sc1\n\t"
      "global_load_dwordx4 %3, %[a], off offset:48 sc1\n\t"
      "s_waitcnt vmcnt(0)"
      : "=&v"(v[0]), "=&v"(v[1]), "=&v"(v[2]), "=&v"(v[3])
      : [a] "v"(p)
      : "memory");
}
DEV void st16_sc1(u32x4* p, u32x4 v) {
  asm volatile("global_store_dwordx4 %0, %1, off sc1" :: "v"(p), "v"(v) : "memory");
}

DEV int anysent(unsigned x) {
  unsigned y = x ^ SENT2;
  return ((y & 0xFFFFu) == 0u) | ((y >> 16) == 0u);
}
DEV int ok16(u32x4 v) {
  return !(anysent(v[0]) | anysent(v[1]) | anysent(v[2]) | anysent(v[3]));
}

// ---------------- prep kernels ----------------
__global__ void k_fillsent(uint4* p, int n8) {
  int i = blockIdx.x * blockDim.x + threadIdx.x;
  if (i < n8) { uint4 s = {SENT2, SENT2, SENT2, SENT2}; p[i] = s; }
}

// conv_w [11][80][256] -> CW [256][896] bf16 (K padded w/ zeros)
__global__ void k_convw(const float* __restrict__ w, ushort* __restrict__ dst) {
  int idx = blockIdx.x * blockDim.x + threadIdx.x;
  if (idx >= F * KC) return;
  int f = idx / KC, kk = idx % KC;
  float v = (kk < KW * CIN) ? w[(size_t)kk * F + f] : 0.f;
  dst[idx] = f2bf(v);
}

// src [K][N] fp32 -> dst [N][K] bf16
__global__ void k_transp(const float* __restrict__ src, ushort* __restrict__ dst, int K, int N) {
  int idx = blockIdx.x * blockDim.x + threadIdx.x;
  if (idx >= K * N) return;
  int n = idx / K, k = idx % K;
  dst[idx] = f2bf(src[(size_t)k * N + n]);
}

// wh [512][2048] fp32 (f and b) -> packed MFMA B-fragments (round-9 32-col layout).
// linear idx = ((((d*16+part)*8+w)*16+kk)*64+lane)*8 + j
__global__ void k_whr(const float* __restrict__ whf, const float* __restrict__ whb,
                      ushort* __restrict__ dst) {
  int idx = blockIdx.x * blockDim.x + threadIdx.x;
  if (idx >= (1 << 21)) return;
  int j = idx & 7, lane = (idx >> 3) & 63, kk = (idx >> 9) & 15;
  int w = (idx >> 13) & 7, part = (idx >> 16) & 15, d = (idx >> 20) & 1;
  int c16 = lane & 15, q = lane >> 4;
  int jj = w * 4 + (c16 >> 2), g = c16 & 3;
  int k = kk * 32 + q * 8 + j;
  int col = g * 512 + part * 32 + jj;
  const float* s = d ? whb : whf;
  dst[idx] = f2bf(s[(size_t)k * G4 + col]);
}

// x [32][2000][80] fp32 -> A0 [nrows][896] bf16 im2col (rows: (pos-pos0)*32+b)
__global__ void k_im2col(const float* __restrict__ x, ushort* __restrict__ A0,
                         int pos0, int nrows) {
  int idx = blockIdx.x * blockDim.x + threadIdx.x;
  if (idx >= nrows * KC) return;
  int row = idx / KC, kk = idx % KC;
  int pos = pos0 + (row >> 5), b = row & 31;
  float v = 0.f;
  if (kk < KW * CIN) {
    int k = kk / CIN, c = kk % CIN;
    int tx = 2 * pos + k - 4;
    if (tx >= 0 && tx < TI) v = x[((size_t)b * TI + tx) * CIN + c];
  }
  A0[idx] = f2bf(v);
}

// ---------------- standalone GEMM (256 thr): conv + fallback path ----------
__global__ __launch_bounds__(256, 2) void k_gemm(const ushort* __restrict__ A,
                                                 const ushort* __restrict__ BT,
                                                 const float* __restrict__ bias,
                                                 ushort* __restrict__ C,
                                                 int N, int K, int relu, int tmode) {
  __shared__ ushort As[128 * 64];
  __shared__ ushort Bs[128 * 64];
  const int tid = threadIdx.x;
  const int lane = tid & 63, wid = tid >> 6;
  const int wm = wid >> 1, wn = wid & 1;
  const int l16 = lane & 15, q = lane >> 4;
  const int bm = blockIdx.x, bn = blockIdx.y;
  const int srow = tid >> 1, scol = (tid & 1) * 32;
  const ushort* ga = A + (size_t)(bm * 128 + srow) * K + scol;
  const ushort* gb = BT + (size_t)(bn * 128 + srow) * K + scol;

  f32x4 acc[4][4] = {};
  uint4 va[4], vb[4];
#pragma unroll
  for (int i = 0; i < 4; i++) { va[i] = ((const uint4*)ga)[i]; vb[i] = ((const uint4*)gb)[i]; }

  for (int k0 = 0; k0 < K; k0 += 64) {
    __syncthreads();
#pragma unroll
    for (int i = 0; i < 4; i++) {
      *(uint4*)&As[srow * 64 + scol + i * 8] = va[i];
      *(uint4*)&Bs[srow * 64 + scol + i * 8] = vb[i];
    }
    __syncthreads();
    if (k0 + 64 < K) {
      const ushort* na = ga + k0 + 64;
      const ushort* nb = gb + k0 + 64;
#pragma unroll
      for (int i = 0; i < 4; i++) { va[i] = ((const uint4*)na)[i]; vb[i] = ((const uint4*)nb)[i]; }
    }
#pragma unroll
    for (int kk = 0; kk < 2; kk++) {
      short8 af[4], bf[4];
#pragma unroll
      for (int mt = 0; mt < 4; mt++)
        af[mt] = *(const short8*)&As[(wm * 64 + mt * 16 + l16) * 64 + kk * 32 + q * 8];
#pragma unroll
      for (int nt = 0; nt < 4; nt++)
        bf[nt] = *(const short8*)&Bs[(wn * 64 + nt * 16 + l16) * 64 + kk * 32 + q * 8];
#pragma unroll
      for (int mt = 0; mt < 4; mt++)
#pragma unroll
        for (int nt = 0; nt < 4; nt++)
          acc[mt][nt] = __builtin_amdgcn_mfma_f32_16x16x32_bf16(af[mt], bf[nt], acc[mt][nt], 0, 0, 0);
    }
  }
  if (tmode == 0) {
#pragma unroll
    for (int mt = 0; mt < 4; mt++) {
#pragma unroll
      for (int nt = 0; nt < 4; nt++) {
        int col = bn * 128 + wn * 64 + nt * 16 + l16;
        float bv = bias[col];
#pragma unroll
        for (int r = 0; r < 4; r++) {
          int row = bm * 128 + wm * 64 + mt * 16 + q * 4 + r;
          float v = acc[mt][nt][r] + bv;
          if (relu) v = fmaxf(v, 0.f);
          C[(size_t)row * N + col] = f2bf(v);
        }
      }
    }
  } else {
#pragma unroll
    for (int mt = 0; mt < 4; mt++) {
#pragma unroll
      for (int nt = 0; nt < 4; nt++) {
        int col = bn * 128 + wn * 64 + nt * 16 + l16;
        float bv = bias[col];
        ushort4 pk;
        pk.x = f2bf(acc[mt][nt][0] + bv);
        pk.y = f2bf(acc[mt][nt][1] + bv);
        pk.z = f2bf(acc[mt][nt][2] + bv);
        pk.w = f2bf(acc[mt][nt][3] + bv);
        int row = bm * 128 + wm * 64 + mt * 16 + q * 4;
        *(ushort4*)&C[(size_t)col * CROWS + row] = pk;
      }
    }
  }
}

// ---------------- dual-direction first-chunk projection (tmode=1), grid (25, 32) --------
__global__ __launch_bounds__(256, 2) void k_proj2(const ushort* __restrict__ Af,
                                                  const ushort* __restrict__ Ab,
                                                  const ushort* __restrict__ BTf,
                                                  const ushort* __restrict__ BTb,
                                                  const float* __restrict__ bf_,
                                                  const float* __restrict__ bb_,
                                                  ushort* __restrict__ Cf,
                                                  ushort* __restrict__ Cb,
                                                  int K) {
  __shared__ ushort As[128 * 64];
  __shared__ ushort Bs[128 * 64];
  const int tid = threadIdx.x;
  const int lane = tid & 63, wid = tid >> 6;
  const int wm = wid >> 1, wn = wid & 1;
  const int l16 = lane & 15, q = lane >> 4;
  const int bm = blockIdx.x;
  const int bwd = blockIdx.y >> 4, bn = blockIdx.y & 15;
  const ushort* A  = bwd ? Ab : Af;
  const ushort* BT = bwd ? BTb : BTf;
  const float* bias = bwd ? bb_ : bf_;
  ushort* C = bwd ? Cb : Cf;
  const int srow = tid >> 1, scol = (tid & 1) * 32;
  const ushort* ga = A + (size_t)(bm * 128 + srow) * K + scol;
  const ushort* gb = BT + (size_t)(bn * 128 + srow) * K + scol;

  f32x4 acc[4][4] = {};
  uint4 va[4], vb[4];
#pragma unroll
  for (int i = 0; i < 4; i++) { va[i] = ((const uint4*)ga)[i]; vb[i] = ((const uint4*)gb)[i]; }

  for (int k0 = 0; k0 < K; k0 += 64) {
    __syncthreads();
#pragma unroll
    for (int i = 0; i < 4; i++) {
      *(uint4*)&As[srow * 64 + scol + i * 8] = va[i];
      *(uint4*)&Bs[srow * 64 + scol + i * 8] = vb[i];
    }
    __syncthreads();
    if (k0 + 64 < K) {
      const ushort* na = ga + k0 + 64;
      const ushort* nb = gb + k0 + 64;
#pragma unroll
      for (int i = 0; i < 4; i++) { va[i] = ((const uint4*)na)[i]; vb[i] = ((const uint4*)nb)[i]; }
    }
#pragma unroll
    for (int kk = 0; kk < 2; kk++) {
      short8 af[4], bf4[4];
#pragma unroll
      for (int mt = 0; mt < 4; mt++)
        af[mt] = *(const short8*)&As[(wm * 64 + mt * 16 + l16) * 64 + kk * 32 + q * 8];
#pragma unroll
      for (int nt = 0; nt < 4; nt++)
        bf4[nt] = *(const short8*)&Bs[(wn * 64 + nt * 16 + l16) * 64 + kk * 32 + q * 8];
#pragma unroll
      for (int mt = 0; mt < 4; mt++)
#pragma unroll
        for (int nt = 0; nt < 4; nt++)
          acc[mt][nt] = __builtin_amdgcn_mfma_f32_16x16x32_bf16(af[mt], bf4[nt], acc[mt][nt], 0, 0, 0);
    }
  }
#pragma unroll
  for (int mt = 0; mt < 4; mt++) {
#pragma unroll
    for (int nt = 0; nt < 4; nt++) {
      int col = bn * 128 + wn * 64 + nt * 16 + l16;
      float bv = bias[col];
      ushort4 pk;
      pk.x = f2bf(acc[mt][nt][0] + bv);
      pk.y = f2bf(acc[mt][nt][1] + bv);
      pk.z = f2bf(acc[mt][nt][2] + bv);
      pk.w = f2bf(acc[mt][nt][3] + bv);
      int row = bm * 128 + wm * 64 + mt * 16 + q * 4;
      *(ushort4*)&C[(size_t)col * CROWS + row] = pk;
    }
  }
}

// ---------------- fused gemm tile (512 thr, waves 0-3 active; barriers block-wide) -------
DEV void gemm_tile512(const ushort* __restrict__ A, const ushort* __restrict__ BT,
                      const float* __restrict__ bias, ushort* __restrict__ C,
                      int K, int bm, int bn, int tid, ushort* As, ushort* Bs) {
  const int lane = tid & 63, wid = tid >> 6;
  const bool act = wid < 4;
  const int wm = (wid >> 1) & 1, wn = wid & 1;
  const int l16 = lane & 15, q = lane >> 4;
  const int srow = (tid & 255) >> 1, scol = (tid & 1) * 32;
  const ushort* ga = A + (size_t)(bm * 128 + srow) * K + scol;
  const ushort* gb = BT + (size_t)(bn * 128 + srow) * K + scol;

  f32x4 acc[4][4] = {};
  uint4 va[4], vb[4];
  if (act) {
#pragma unroll
    for (int i = 0; i < 4; i++) { va[i] = ((const uint4*)ga)[i]; vb[i] = ((const uint4*)gb)[i]; }
  }
  for (int k0 = 0; k0 < K; k0 += 64) {
    __syncthreads();
    if (act) {
#pragma unroll
      for (int i = 0; i < 4; i++) {
        *(uint4*)&As[srow * 64 + scol + i * 8] = va[i];
        *(uint4*)&Bs[srow * 64 + scol + i * 8] = vb[i];
      }
    }
    __syncthreads();
    if (act) {
      if (k0 + 64 < K) {
        const ushort* na = ga + k0 + 64;
        const ushort* nb = gb + k0 + 64;
#pragma unroll
        for (int i = 0; i < 4; i++) { va[i] = ((const uint4*)na)[i]; vb[i] = ((const uint4*)nb)[i]; }
      }
#pragma unroll
      for (int kk = 0; kk < 2; kk++) {
        short8 af[4], bf[4];
#pragma unroll
        for (int mt = 0; mt < 4; mt++)
          af[mt] = *(const short8*)&As[(wm * 64 + mt * 16 + l16) * 64 + kk * 32 + q * 8];
#pragma unroll
        for (int nt = 0; nt < 4; nt++)
          bf[nt] = *(const short8*)&Bs[(wn * 64 + nt * 16 + l16) * 64 + kk * 32 + q * 8];
#pragma unroll
        for (int mt = 0; mt < 4; mt++)
#pragma unroll
          for (int nt = 0; nt < 4; nt++)
            acc[mt][nt] = __builtin_amdgcn_mfma_f32_16x16x32_bf16(af[mt], bf[nt], acc[mt][nt], 0, 0, 0);
      }
    }
  }
  if (act) {
#pragma unroll
    for (int mt = 0; mt < 4; mt++) {
#pragma unroll
      for (int nt = 0; nt < 4; nt++) {
        int col = bn * 128 + wn * 64 + nt * 16 + l16;
        float bv = bias[col];
        ushort4 pk;
        pk.x = f2bf(acc[mt][nt][0] + bv);
        pk.y = f2bf(acc[mt][nt][1] + bv);
        pk.z = f2bf(acc[mt][nt][2] + bv);
        pk.w = f2bf(acc[mt][nt][3] + bv);
        int row = bm * 128 + wm * 64 + mt * 16 + q * 4;
        *(ushort4*)&C[(size_t)col * CROWS + row] = pk;
      }
    }
  }
}

// ---------------- fused persistent rec + next-chunk projections ----------
// grid 256 x 512. Blocks 0-31: round-9 rec core (block=(d<<4)|part, 32 cols each,
// wf[16]=64 regs, sentinel poll, staged sc1 stores, own-slice LDS bypass).
// Blocks 32-255: grid-stride over njobs projection tiles for chunk p+1 (write other xg buf).
__global__ __launch_bounds__(512, 1) void k_recf(const ushort* __restrict__ xgf,
                                                 const ushort* __restrict__ xgb,
                                                 const ushort* __restrict__ whr,
                                                 ushort* __restrict__ hout,
                                                 float* __restrict__ cstbuf,
                                                 int s0,
                                                 const ushort* __restrict__ gAf,
                                                 const ushort* __restrict__ gAb,
                                                 const ushort* __restrict__ gBTf,
                                                 const ushort* __restrict__ gBTb,
                                                 const float* __restrict__ gbf,
                                                 const float* __restrict__ gbb,
                                                 ushort* __restrict__ gCf,
                                                 ushort* __restrict__ gCb,
                                                 int gK, int njobs) {
  __shared__ union SM {
    struct { ushort hs[32 * 512]; ushort hstage[32 * 32]; } r;  // 34KB rec
    struct { ushort As[128 * 64]; ushort Bs[128 * 64]; } g;     // 32KB gemm
  } sm;
  const int tid = threadIdx.x;

  if (blockIdx.x >= 32) {
    // ---- fused projection gemm blocks ----
    for (int job = (int)blockIdx.x - 32; job < njobs; job += GEMM_BLKS) {
      int dir = job / 400, t = job % 400, bm = t / 16, bn = t % 16;
      gemm_tile512(dir ? gAb : gAf, dir ? gBTb : gBTf, dir ? gbb : gbf, dir ? gCb : gCf,
                   gK, bm, bn, tid, sm.g.As, sm.g.Bs);
    }
    return;
  }

  // ---- rec core (round-9 structure) ----
  const int lane = tid & 63, w = tid >> 6;
  const int part = blockIdx.x & 15, d = blockIdx.x >> 4;
  const int l16 = lane & 15, q = lane >> 4;
  const ushort* xg = d ? xgb : xgf;   // transposed layout [2048][CROWS]
  float* cs = cstbuf + ((size_t)blockIdx.x * 512 + tid) * 8;

  short8 wf[16];
  {
    const ushort* p = whr + (((size_t)(d * 16 + part) * 8 + w) * 16 * 64 + lane) * 8;
#pragma unroll
    for (int kk = 0; kk < 16; kk++) wf[kk] = *(const short8*)(p + (size_t)kk * 64 * 8);
  }
  const int jj = w * 4 + (l16 >> 2), g = l16 & 3;
  const int gcol = g * 512 + part * 32 + jj;
  float cst[2][4];
#pragma unroll
  for (int mt = 0; mt < 2; mt++)
#pragma unroll
    for (int r = 0; r < 4; r++) cst[mt][r] = (s0 == 0) ? 0.f : cs[mt * 4 + r];

  for (int ls = 0; ls < CH; ls++) {
    const int s = s0 + ls;
    const int pos = d ? (999 - s) : s;
    const int lp = d ? (CH - 1 - ls) : ls;
    const ushort* xc = xg + (size_t)gcol * CROWS + lp * 32 + q * 4;
    ushort4 xt0 = *(const ushort4*)(xc);
    ushort4 xt1 = *(const ushort4*)(xc + 16);

    if (s == 0) {
      uint4 z4 = {0, 0, 0, 0};
#pragma unroll
      for (int i = 0; i < 4; i++) ((uint4*)sm.r.hs)[tid * 4 + i] = z4;
    } else {
      const int row = tid >> 4, p16 = tid & 15;
      u32x4 v[4];
      int own = (ls > 0) && (p16 == part);
      if (own) {
        // own slice: hstage still holds step s-1 values (LDS, no global round-trip)
#pragma unroll
        for (int k = 0; k < 4; k++)
          v[k] = *(const u32x4*)((char*)sm.r.hstage + row * 64 + k * 16);
      }
      const int ppos = d ? pos + 1 : pos - 1;
      const u32x4* gb = (const u32x4*)(hout + ((size_t)ppos * 32 + row) * 1024 +
                                       d * 512 + p16 * 32);
      int done = own;
      while (!__all(done)) {
        if (!done) {
          ld64_sc1(gb, v);
          done = ok16(v[0]) & ok16(v[1]) & ok16(v[2]) & ok16(v[3]);
        }
      }
      const int swz = (row & 7) << 4;
      char* L = (char*)sm.r.hs + row * 1024;
      const int cb = p16 * 64;
#pragma unroll
      for (int k = 0; k < 4; k++)
        *(u32x4*)(L + ((cb + k * 16) ^ swz)) = v[k];
    }
    __syncthreads();

    f32x4 za[2] = {};
#pragma unroll
    for (int kk = 0; kk < 16; kk++) {
#pragma unroll
      for (int mt = 0; mt < 2; mt++) {
        int row = mt * 16 + l16;
        int cb = kk * 64 + q * 16;
        short8 a = *(const short8*)((char*)sm.r.hs + row * 1024 + (cb ^ ((row & 7) << 4)));
        za[mt] = __builtin_amdgcn_mfma_f32_16x16x32_bf16(a, wf[kk], za[mt], 0, 0, 0);
      }
    }

#pragma unroll
    for (int mt = 0; mt < 2; mt++) {
#pragma unroll
      for (int r = 0; r < 4; r++) {
        int bt = mt * 16 + q * 4 + r;
        ushort xr = (mt == 0) ? ((r == 0) ? xt0.x : (r == 1) ? xt0.y : (r == 2) ? xt0.z : xt0.w)
                              : ((r == 0) ? xt1.x : (r == 1) ? xt1.y : (r == 2) ? xt1.z : xt1.w);
        float z = za[mt][r] + bf2f(xr);
        int base = lane & ~3;
        float zi = __shfl(z, base + 0);
        float zf = __shfl(z, base + 1);
        float zg = __shfl(z, base + 2);
        float zo = __shfl(z, base + 3);
        float cn = sigm(zf) * cst[mt][r] + sigm(zi) * tanhft(zg);
        cst[mt][r] = cn;
        float hv = sigm(zo) * tanhft(cn);
        if (g == 0) sm.r.hstage[bt * 32 + jj] = f2bf(hv);
      }
    }
    __syncthreads();  // hstage complete; hs free for next iteration
    // coalesced producer store: 128 threads x 16B = 2KB slice, sc1 fire-and-forget
    if ((lane & 12) == 0) {
      const int rr = 4 * w + (lane >> 4);
      const int ck = lane & 3;
      u32x4 dv = *(u32x4*)((char*)sm.r.hstage + rr * 64 + ck * 16);
      st16_sc1((u32x4*)(hout + ((size_t)pos * 32 + rr) * 1024 + d * 512 + part * 32) + ck, dv);
    }
  }
#pragma unroll
  for (int mt = 0; mt < 2; mt++)
#pragma unroll
    for (int r = 0; r < 4; r++) cs[mt * 4 + r] = cst[mt][r];
}

// ---------------- dense: out[b][pos][29] = h2[row,1024] . W[1024,29] + bias ------------
__global__ __launch_bounds__(256, 2) void k_dense(const ushort* __restrict__ h2,
                                                  const float* __restrict__ wd,
                                                  const float* __restrict__ bd,
                                                  float* __restrict__ out) {
  __shared__ ushort rs[8 * 1024];
  const int tid = threadIdx.x;
  const int r0 = blockIdx.x * 8;
  const uint4* src = (const uint4*)(h2 + (size_t)r0 * 1024);
#pragma unroll
  for (int i = 0; i < 4; i++) ((uint4*)rs)[tid * 4 + i] = src[tid * 4 + i];
  __syncthreads();
  if (tid < 8 * V) {
    const int rr = tid / V, v = tid % V;
    float acc = bd[v];
    const ushort* rp = rs + rr * 1024;
#pragma unroll 8
    for (int k = 0; k < 1024; k++) acc += bf2f(rp[k]) * wd[(size_t)k * V + v];
    const int row = r0 + rr, pos = row >> 5, b = row & 31;
    out[((size_t)b * TT + pos) * V + v] = acc;
  }
}

// ---------------- host ----------------
extern "C" void kernel_launch(void* const* d_in, const int* in_sizes, int n_in,
                              void* d_out, int out_size, void* d_ws, size_t ws_size,
                              hipStream_t stream) {
  const float* x      = (const float*)d_in[0];
  const float* conv_w = (const float*)d_in[1];
  const float* conv_b = (const float*)d_in[2];
  const float* wi1f = (const float*)d_in[3];
  const float* wh1f = (const float*)d_in[4];
  const float* b1f  = (const float*)d_in[5];
  const float* wi1b = (const float*)d_in[6];
  const float* wh1b = (const float*)d_in[7];
  const float* b1b  = (const float*)d_in[8];
  const float* wi2f = (const float*)d_in[9];
  const float* wh2f = (const float*)d_in[10];
  const float* b2f  = (const float*)d_in[11];
  const float* wi2b = (const float*)d_in[12];
  const float* wh2b = (const float*)d_in[13];
  const float* b2b  = (const float*)d_in[14];
  const float* wd   = (const float*)d_in[15];
  const float* bd   = (const float*)d_in[16];
  float* out = (float*)d_out;

  char* ws = (char*)d_ws;
  size_t o = 0;
  auto alloc = [&](size_t sz) { size_t r = o; o = (o + sz + 255) & ~(size_t)255; return r; };
  const size_t XG_SZ = (size_t)CROWS * G4 * 2;          // 13.1MB per xg buffer
  const size_t oH2  = alloc((size_t)MROWS * 1024 * 2);  // 65.5MB; Y overlays first 16.4MB
  const size_t oY   = oH2;
  const size_t oXGF0 = alloc(XG_SZ);
  const size_t oXGB0 = alloc(XG_SZ);
  const size_t oH1  = alloc((size_t)MROWS * 1024 * 2);  // A0 (57.3MB) overlays until fillsent
  const size_t oA0  = oH1;
  const size_t oCW  = alloc((size_t)F * KC * 2);
  const size_t oW1F = alloc((size_t)G4 * F * 2);
  const size_t oW1B = alloc((size_t)G4 * F * 2);
  const size_t oW2F = alloc((size_t)G4 * 1024 * 2);
  const size_t oW2B = alloc((size_t)G4 * 1024 * 2);
  const size_t oR1  = alloc((size_t)(1 << 21) * 2);
  const size_t oR2  = alloc((size_t)(1 << 21) * 2);
  const size_t oCST = alloc((size_t)32 * 512 * 8 * 4);
  const size_t base_need = o;
  if (ws_size < base_need) return;
  // optional double-buffer for xg (enables fused next-chunk projections)
  size_t oXGF1 = oXGF0, oXGB1 = oXGB0;
  bool dbuf = false;
  {
    size_t o2 = o;
    size_t f1 = o2; o2 = (o2 + XG_SZ + 255) & ~(size_t)255;
    size_t b1 = o2; o2 = (o2 + XG_SZ + 255) & ~(size_t)255;
    if (ws_size >= o2) { dbuf = true; oXGF1 = f1; oXGB1 = b1; }
  }

  ushort* H2  = (ushort*)(ws + oH2);
  ushort* Y   = (ushort*)(ws + oY);
  ushort* XGF[2] = {(ushort*)(ws + oXGF0), (ushort*)(ws + oXGF1)};
  ushort* XGB[2] = {(ushort*)(ws + oXGB0), (ushort*)(ws + oXGB1)};
  ushort* H1  = (ushort*)(ws + oH1);
  ushort* A0  = (ushort*)(ws + oA0);
  ushort* CW  = (ushort*)(ws + oCW);
  ushort* W1F = (ushort*)(ws + oW1F);
  ushort* W1B = (ushort*)(ws + oW1B);
  ushort* W2F = (ushort*)(ws + oW2F);
  ushort* W2B = (ushort*)(ws + oW2B);
  ushort* R1  = (ushort*)(ws + oR1);
  ushort* R2  = (ushort*)(ws + oR2);
  float*  CST = (float*)(ws + oCST);

  const int N8 = MROWS * 1024 / 8;
  hipLaunchKernelGGL(k_convw, dim3((F * KC + 255) / 256), dim3(256), 0, stream, conv_w, CW);
  hipLaunchKernelGGL(k_transp, dim3((F * G4 + 255) / 256), dim3(256), 0, stream, wi1f, W1F, F, G4);
  hipLaunchKernelGGL(k_transp, dim3((F * G4 + 255) / 256), dim3(256), 0, stream, wi1b, W1B, F, G4);
  hipLaunchKernelGGL(k_transp, dim3((1024 * G4 + 255) / 256), dim3(256), 0, stream, wi2f, W2F, 1024, G4);
  hipLaunchKernelGGL(k_transp, dim3((1024 * G4 + 255) / 256), dim3(256), 0, stream, wi2b, W2B, 1024, G4);
  hipLaunchKernelGGL(k_whr, dim3((1 << 21) / 256), dim3(256), 0, stream, wh1f, wh1b, R1);
  hipLaunchKernelGGL(k_whr, dim3((1 << 21) / 256), dim3(256), 0, stream, wh2f, wh2b, R2);

  // single-pass conv: full im2col into H1 region (dead until fillsent), one GEMM -> Y
  hipLaunchKernelGGL(k_im2col, dim3((MROWS * KC + 255) / 256), dim3(256), 0, stream,
                     x, A0, 0, MROWS);
  hipLaunchKernelGGL(k_gemm, dim3(MROWS / 128, F / 128), dim3(256), 0, stream,
                     A0, CW, conv_b, Y, F, KC, 1, 0);
  // now A0 is dead -> sentinel-fill H1
  hipLaunchKernelGGL(k_fillsent, dim3((N8 + 255) / 256), dim3(256), 0, stream, (uint4*)H1, N8);

  // ---- layer 1 ----
  hipLaunchKernelGGL(k_proj2, dim3(CROWS / 128, 32), dim3(256), 0, stream,
                     Y, Y + (size_t)9 * CROWS * F, W1F, W1B, b1f, b1b,
                     XGF[0], XGB[0], F);
  for (int p = 0; p < NCH; ++p) {
    const int q = p + 1;
    const bool fuse = dbuf && q < NCH;
    hipLaunchKernelGGL(k_recf, dim3(32 + GEMM_BLKS), dim3(512), 0, stream,
                       XGF[p & 1], XGB[p & 1], R1, H1, CST, p * CH,
                       fuse ? Y + (size_t)q * CROWS * F : (const ushort*)nullptr,
                       fuse ? Y + (size_t)(9 - q) * CROWS * F : (const ushort*)nullptr,
                       W1F, W1B, b1f, b1b,
                       XGF[q & 1], XGB[q & 1], F, fuse ? PROJ_JOBS : 0);
    if (!dbuf && q < NCH) {
      hipLaunchKernelGGL(k_proj2, dim3(CROWS / 128, 32), dim3(256), 0, stream,
                         Y + (size_t)q * CROWS * F, Y + (size_t)(9 - q) * CROWS * F,
                         W1F, W1B, b1f, b1b, XGF[q & 1], XGB[q & 1], F);
    }
  }

  // sentinel-fill H2 (Y dead: last proj1 consumer finished), before layer-2 recurrence
  hipLaunchKernelGGL(k_fillsent, dim3((N8 + 255) / 256), dim3(256), 0, stream, (uint4*)H2, N8);

  // ---- layer 2 ----
  hipLaunchKernelGGL(k_proj2, dim3(CROWS / 128, 32), dim3(256), 0, stream,
                     H1, H1 + (size_t)9 * CROWS * 1024, W2F, W2B, b2f, b2b,
                     XGF[0], XGB[0], 1024);
  for (int p = 0; p < NCH; ++p) {
    const int q = p + 1;
    const bool fuse = dbuf && q < NCH;
    hipLaunchKernelGGL(k_recf, dim3(32 + GEMM_BLKS), dim3(512), 0, stream,
                       XGF[p & 1], XGB[p & 1], R2, H2, CST, p * CH,
                       fuse ? H1 + (size_t)q * CROWS * 1024 : (const ushort*)nullptr,
                       fuse ? H1 + (size_t)(9 - q) * CROWS * 1024 : (const ushort*)nullptr,
                       W2F, W2B, b2f, b2b,
                       XGF[q & 1], XGB[q & 1], 1024, fuse ? PROJ_JOBS : 0);
    if (!dbuf && q < NCH) {
      hipLaunchKernelGGL(k_proj2, dim3(CROWS / 128, 32), dim3(256), 0, stream,
                         H1 + (size_t)q * CROWS * 1024, H1 + (size_t)(9 - q) * CROWS * 1024,
                         W2F, W2B, b2f, b2b, XGF[q & 1], XGB[q & 1], 1024);
    }
  }
  // dense
  hipLaunchKernelGGL(k_dense, dim3(MROWS / 8), dim3(256), 0, stream, H2, wd, bd, out);
}